// Round 5
// baseline (535.651 us; speedup 1.0000x reference)
//
#include <hip/hip_runtime.h>
#include <math.h>

#define S_LEN 2048
#define HID 2048
#define NH 16
#define NKV 4
#define DH 128
#define CACHE_LEN 2048
#define QKV_W 3072   // q(2048) | k(512) | v(512) packed per row
#define SCALE 0.08838834764831845f
#define EPS 1e-6f
#define LYRA_C 12.0f // fixed softmax max-bound: |scores| <= ~19, exp(s-12) safe

typedef short bf16x8 __attribute__((ext_vector_type(8)));
typedef float f32x4 __attribute__((ext_vector_type(4)));

static __device__ __forceinline__ short f2bf(float x) {
  union { float f; unsigned u; } v; v.f = x;
  unsigned r = (v.u + 0x7FFF + ((v.u >> 16) & 1)) >> 16;
  return (short)r;
}

static __device__ __forceinline__ float bf2f(short h) {
  union { unsigned u; float f; } v;
  v.u = ((unsigned)(unsigned short)h) << 16;
  return v.f;
}

#define GLDS16(g, l)                                                      \
  __builtin_amdgcn_global_load_lds(                                       \
      (const __attribute__((address_space(1))) unsigned int*)(g),         \
      (__attribute__((address_space(3))) unsigned int*)(l), 16, 0, 0)

// ---------------------------------------------------------------------------
// fp32 -> bf16 pack, 8 elements/thread.
// ---------------------------------------------------------------------------
__global__ __launch_bounds__(256) void pack_bf16(
    const float* __restrict__ src, short* __restrict__ dst) {
  const int i = (blockIdx.x * 256 + threadIdx.x) * 8;
  float4 a = *(const float4*)(src + i);
  float4 b = *(const float4*)(src + i + 4);
  bf16x8 o;
  o[0] = f2bf(a.x); o[1] = f2bf(a.y); o[2] = f2bf(a.z); o[3] = f2bf(a.w);
  o[4] = f2bf(b.x); o[5] = f2bf(b.y); o[6] = f2bf(b.z); o[7] = f2bf(b.w);
  *(bf16x8*)(dst + i) = o;
}

// ---------------------------------------------------------------------------
// bf16 MFMA GEMM: C[M x N] fp32 = A[M x K]bf16 * B[N x K]bf16^T.
// ---------------------------------------------------------------------------
__global__ __launch_bounds__(256) void gemm_bf16(
    const short* __restrict__ A, const short* __restrict__ B,
    float* __restrict__ C, int K, int ldc) {
  __shared__ short sA[4096];
  __shared__ short sB[4096];
  const int t = threadIdx.x;
  const int w = t >> 6;
  const int lane = t & 63;
  const int quad = lane >> 4;
  const int l16 = lane & 15;
  const int tm = blockIdx.y * 128;
  const int tn = blockIdx.x * 128;
  const int srow = lane >> 2;
  const int scol = (lane & 3) * 8;
  const int mblk = (w & 1) * 64;
  const int nblk = (w >> 1) * 64;
  f32x4 acc[4][4];
#pragma unroll
  for (int i = 0; i < 4; ++i)
#pragma unroll
    for (int j = 0; j < 4; ++j) acc[i][j] = (f32x4){0.f, 0.f, 0.f, 0.f};

  const short* Ab = A + (size_t)(tm + w * 32 + srow) * K + scol;
  const short* Bb = B + (size_t)(tn + w * 32 + srow) * K + scol;
  const size_t rstep = (size_t)16 * K;

  for (int k0 = 0; k0 < K; k0 += 32) {
    GLDS16(Ab + k0, sA + (w * 2 + 0) * 512);
    GLDS16(Ab + rstep + k0, sA + (w * 2 + 1) * 512);
    GLDS16(Bb + k0, sB + (w * 2 + 0) * 512);
    GLDS16(Bb + rstep + k0, sB + (w * 2 + 1) * 512);
    __syncthreads();
    bf16x8 af[4], bfv[4];
#pragma unroll
    for (int ms = 0; ms < 4; ++ms)
      af[ms] = *(const bf16x8*)&sA[(mblk + ms * 16 + l16) * 32 + quad * 8];
#pragma unroll
    for (int ns = 0; ns < 4; ++ns)
      bfv[ns] = *(const bf16x8*)&sB[(nblk + ns * 16 + l16) * 32 + quad * 8];
#pragma unroll
    for (int ms = 0; ms < 4; ++ms)
#pragma unroll
      for (int ns = 0; ns < 4; ++ns)
        acc[ms][ns] = __builtin_amdgcn_mfma_f32_16x16x32_bf16(
            af[ms], bfv[ns], acc[ms][ns], 0, 0, 0);
    __syncthreads();
  }
#pragma unroll
  for (int ms = 0; ms < 4; ++ms)
#pragma unroll
    for (int ns = 0; ns < 4; ++ns) {
      const int row = tm + mblk + ms * 16 + quad * 4;
      const int col = tn + nblk + ns * 16 + l16;
#pragma unroll
      for (int r = 0; r < 4; ++r)
        C[(size_t)(row + r) * ldc + col] = acc[ms][ns][r];
    }
}

// ---------------------------------------------------------------------------
// RMSNorm(+1+w) then RoPE, in-place on q (16 heads) and k (4 heads).
// ---------------------------------------------------------------------------
__global__ __launch_bounds__(256) void rms_rope(
    float* __restrict__ qkv,
    const float* __restrict__ cosb, const float* __restrict__ sinb,
    const float* __restrict__ qw, const float* __restrict__ kw) {
  const int unit = blockIdx.x * 4 + (threadIdx.x >> 6);
  const int lane = threadIdx.x & 63;
  const int total_q = S_LEN * NH;
  float* base;
  const float* w;
  int pos;
  if (unit < total_q) {
    pos = unit >> 4;
    int head = unit & 15;
    base = qkv + (size_t)pos * QKV_W + head * DH;
    w = qw;
  } else {
    int u = unit - total_q;
    pos = u >> 2;
    int head = u & 3;
    base = qkv + (size_t)pos * QKV_W + 2048 + head * DH;
    w = kw;
  }
  float x0 = base[lane];
  float x1 = base[lane + 64];
  float ss = x0 * x0 + x1 * x1;
#pragma unroll
  for (int off = 32; off > 0; off >>= 1) ss += __shfl_xor(ss, off);
  float r = rsqrtf(ss * (1.0f / 128.0f) + EPS);
  float n0 = x0 * r * (1.0f + w[lane]);
  float n1 = x1 * r * (1.0f + w[lane + 64]);
  float c0 = cosb[(size_t)pos * DH + lane];
  float c1 = cosb[(size_t)pos * DH + lane + 64];
  float s0 = sinb[(size_t)pos * DH + lane];
  float s1 = sinb[(size_t)pos * DH + lane + 64];
  base[lane]      = n0 * c0 - n1 * s0;
  base[lane + 64] = n1 * c1 + n0 * s1;
}

// ---------------------------------------------------------------------------
// Pack K (cache ++ roped k) -> bf16 Kbf[4][4096][128], PRE-SWIZZLED within
// each 128-elem row: element d stored at d ^ ((key&7)<<3).  For current keys
// (>= CACHE_LEN) also emit the bf16 residual (lo = x - bf16(x)) to Klo
// [4][2048][128], same swizzle — used by vanilla_attn's split-precision QK.
// ---------------------------------------------------------------------------
__global__ __launch_bounds__(256) void pack_k(
    const float* __restrict__ qkv, const float* __restrict__ kcache,
    short* __restrict__ Kbf, short* __restrict__ Klo) {
  const int idx = blockIdx.x * 256 + threadIdx.x;
  const int e4 = idx * 4;
  const int kvh = e4 >> 19;
  const int rem = e4 & ((1 << 19) - 1);
  const int key = rem >> 7;
  const int d = rem & 127;
  const int dsw = d ^ ((key & 7) << 3);       // in-row XOR swizzle (8-elem units)
  if (key < CACHE_LEN) {
    float4 v = *(const float4*)(kcache + (((size_t)kvh * CACHE_LEN + key) << 7) + d);
    short4 o;
    o.x = f2bf(v.x); o.y = f2bf(v.y); o.z = f2bf(v.z); o.w = f2bf(v.w);
    *(short4*)(Kbf + (size_t)(e4 - d) + dsw) = o;
  } else {
    float4 v = *(const float4*)(qkv + (size_t)(key - CACHE_LEN) * QKV_W + 2048 + kvh * DH + d);
    short4 o;
    o.x = f2bf(v.x); o.y = f2bf(v.y); o.z = f2bf(v.z); o.w = f2bf(v.w);
    *(short4*)(Kbf + (size_t)(e4 - d) + dsw) = o;
    short4 ol;
    ol.x = f2bf(v.x - bf2f(o.x));
    ol.y = f2bf(v.y - bf2f(o.y));
    ol.z = f2bf(v.z - bf2f(o.z));
    ol.w = f2bf(v.w - bf2f(o.w));
    *(short4*)(Klo + ((size_t)kvh * 2048 + (key - CACHE_LEN)) * 128 + dsw) = ol;
  }
}

// ---------------------------------------------------------------------------
// Pack V transposed -> bf16 Vt[4][128][4096], PRE-SWIZZLED within each
// 64-key chunk: key c stored at c ^ ((d&7)<<3).
// ---------------------------------------------------------------------------
__global__ __launch_bounds__(256) void pack_vt(
    const float* __restrict__ qkv, const float* __restrict__ vcache,
    short* __restrict__ Vt) {
  __shared__ float tile[64][65];
  const int key0 = blockIdx.x * 64;
  const int d0 = blockIdx.y * 64;
  const int kvh = blockIdx.z;
  const int t = threadIdx.x;
  const int c = t & 63;
  const int r0 = t >> 6;
#pragma unroll
  for (int i = 0; i < 16; ++i) {
    int r = r0 + i * 4;
    int key = key0 + r;
    float v;
    if (key < CACHE_LEN)
      v = vcache[(((size_t)kvh * CACHE_LEN + key) << 7) + d0 + c];
    else
      v = qkv[(size_t)(key - CACHE_LEN) * QKV_W + 2560 + kvh * DH + d0 + c];
    tile[r][c] = v;
  }
  __syncthreads();
#pragma unroll
  for (int i = 0; i < 16; ++i) {
    int wr = r0 + i * 4;
    int csw = c ^ (((d0 + wr) & 7) << 3);     // in-chunk XOR swizzle
    Vt[((size_t)kvh * DH + d0 + wr) * 4096 + key0 + csw] = f2bf(tile[c][wr]);
  }
}

// ---------------------------------------------------------------------------
// Stage one 64-key K tile (64 rows x 256B = 16KB) into LDS via
// global_load_lds, 4 waves x 4 GLDS.  Global pre-swizzled, LDS linear.
// ---------------------------------------------------------------------------
static __device__ __forceinline__ void stage_k64(
    const short* Kb, short* buf, int key0, int w, int lane) {
#pragma unroll
  for (int i = 0; i < 4; ++i)
    GLDS16(Kb + ((size_t)key0 + w * 16 + i * 4) * 128 + lane * 8,
           buf + (w * 16 + i * 4) * 128);
}

// ---------------------------------------------------------------------------
// Lyra attention v3: grid (hj=8, qt2=64), 256 threads = 2 row-waves x 2
// key-waves, 32 q-rows per block, 64-key tiles.  LDS = K dbuf 32KB + sP 8KB
// = ~40KB -> 2 INDEPENDENT blocks/CU (separate barrier domains desync the
// QK->exp->PV serial chains; in-block waves are barrier-locked in phase).
// V is NOT staged: PV fragments are per-lane 16B loads from the L2-pinned
// Vtb (issued first after the barrier -> compiler waits vmcnt(4), K-staging
// GLDS stays in flight).  Fixed-shift softmax, ones-MFMA row sums, 2-way
// wc-merge epilogue.  id%8==hj pins each kvh's K+V to one XCD L2.
// ---------------------------------------------------------------------------
__global__ __launch_bounds__(256) void lyra_attn(
    const float* __restrict__ qkv,
    const short* __restrict__ Kbf,   // [4][4096][128] pre-swizzled rows
    const short* __restrict__ Vtb,   // [4][128][4096] pre-swizzled 64-chunks
    short* __restrict__ combined_bf) {
  __shared__ short sK[2][8192];      // 2 x (64 keys x 128 e)
  __shared__ short sP[4][1024];      // per-wave [16][64], slot-XOR swizzled
  __shared__ float sL[32];
  const int hj = blockIdx.x;
  const int qt2 = blockIdx.y;        // 0..63
  const int kvh = hj >> 1;
  const int t = threadIdx.x;
  const int w = t >> 6;              // 0..3
  const int lane = t & 63;
  const int quad = lane >> 4;
  const int l16 = lane & 15;
  const int wr = w >> 1;             // row-wave: rows wr*16..+16
  const int wc = w & 1;              // key-wave: 32-key slice
  const int row0 = qt2 * 32;
  const int rbase = row0 + wr * 16 + quad * 4;
  const int swx = (l16 & 7) << 4;    // byte XOR for swizzled ds_read_b128
  const int vsw = (l16 & 7) << 3;    // element XOR for direct global reads

  bf16x8 qf[4];
  {
    const float* qrow =
        qkv + (size_t)(row0 + wr * 16 + l16) * QKV_W + (8 + hj) * DH;
#pragma unroll
    for (int ks = 0; ks < 4; ++ks) {
      float4 f0 = *(const float4*)(qrow + ks * 32 + quad * 8);
      float4 f1 = *(const float4*)(qrow + ks * 32 + quad * 8 + 4);
      qf[ks][0] = f2bf(f0.x); qf[ks][1] = f2bf(f0.y);
      qf[ks][2] = f2bf(f0.z); qf[ks][3] = f2bf(f0.w);
      qf[ks][4] = f2bf(f1.x); qf[ks][5] = f2bf(f1.y);
      qf[ks][6] = f2bf(f1.z); qf[ks][7] = f2bf(f1.w);
    }
  }
  bf16x8 onesf;
#pragma unroll
  for (int i = 0; i < 8; ++i) onesf[i] = (short)0x3F80;  // bf16 1.0

  f32x4 accO[8];
#pragma unroll
  for (int i = 0; i < 8; ++i) accO[i] = (f32x4){0.f, 0.f, 0.f, 0.f};
  f32x4 accL = (f32x4){0.f, 0.f, 0.f, 0.f};

  const short* Kb = Kbf + (size_t)kvh * 4096 * DH;
  const short* Vb = Vtb + (size_t)kvh * DH * 4096;

  stage_k64(Kb, &sK[0][0], 0, w, lane);

  short* sPw = &sP[w][0];
  int b = 0;
  for (int kt = 0; kt < 64; ++kt) {
    asm volatile("s_waitcnt vmcnt(0)" ::: "memory");
    __builtin_amdgcn_s_barrier();
    __builtin_amdgcn_sched_barrier(0);

    // V fragments for THIS tile, per-lane from L2 (issued before staging so
    // their wait leaves the staging GLDS in flight).
    bf16x8 bvg[8];
    const int vcol = kt * 64 + ((wc * 32 + quad * 8) ^ vsw);
#pragma unroll
    for (int t8 = 0; t8 < 8; ++t8)
      bvg[t8] = *(const bf16x8*)(Vb + (size_t)(t8 * 16 + l16) * 4096 + vcol);

    if (kt < 63) stage_k64(Kb, &sK[b ^ 1][0], (kt + 1) * 64, w, lane);

    const char* Ksc = (const char*)&sK[b][0];

    // QK^T: 16 rows x 32 keys
    f32x4 accS[2];
#pragma unroll
    for (int s = 0; s < 2; ++s) accS[s] = (f32x4){0.f, 0.f, 0.f, 0.f};
    __builtin_amdgcn_s_setprio(1);
#pragma unroll
    for (int s = 0; s < 2; ++s) {
      const char* krow = Ksc + (wc * 32 + s * 16 + l16) * 256;
#pragma unroll
      for (int ks = 0; ks < 4; ++ks) {
        bf16x8 bk = *(const bf16x8*)(krow + ((ks * 64 + quad * 16) ^ swx));
        accS[s] = __builtin_amdgcn_mfma_f32_16x16x32_bf16(qf[ks], bk, accS[s],
                                                          0, 0, 0);
      }
    }
    __builtin_amdgcn_s_setprio(0);

    // fixed-max softmax: p = exp(s*SCALE - 12); mask (+1.0) iff
    // col - CACHE_LEN > row (false automatically for cached keys).
    const int base = kt * 64 + wc * 32;
#pragma unroll
    for (int s = 0; s < 2; ++s) {
      const int col = base + s * 16 + l16;
#pragma unroll
      for (int r = 0; r < 4; ++r) {
        const int row = quad * 4 + r;
        float sc = accS[s][r] * SCALE;
        if ((col - CACHE_LEN) > (rbase + r)) sc += 1.0f;
        const int sl = (s * 2 + (l16 >> 3)) ^ (row & 7);
        sPw[row * 64 + sl * 8 + (l16 & 7)] = f2bf(__expf(sc - LYRA_C));
      }
    }

    // PV + row-sum over this wave's 32-key slice
    __builtin_amdgcn_s_setprio(1);
    bf16x8 ap = *(const bf16x8*)&sPw[l16 * 64 + ((quad ^ (l16 & 7)) << 3)];
    accL = __builtin_amdgcn_mfma_f32_16x16x32_bf16(ap, onesf, accL, 0, 0, 0);
#pragma unroll
    for (int t8 = 0; t8 < 8; ++t8)
      accO[t8] = __builtin_amdgcn_mfma_f32_16x16x32_bf16(ap, bvg[t8], accO[t8],
                                                         0, 0, 0);
    __builtin_amdgcn_s_setprio(0);

    b ^= 1;
  }

  // epilogue: merge the 2 wc-partials through dead sK, normalize, write.
  __syncthreads();
  float* sO = (float*)&sK[0][0];     // [32 rows][128] f32 = 16 KB
  if (wc == 1) {
#pragma unroll
    for (int t8 = 0; t8 < 8; ++t8)
#pragma unroll
      for (int r = 0; r < 4; ++r)
        sO[(wr * 16 + quad * 4 + r) * 128 + t8 * 16 + l16] = accO[t8][r];
    if (l16 == 0) {
#pragma unroll
      for (int r = 0; r < 4; ++r) sL[wr * 16 + quad * 4 + r] = accL[r];
    }
  }
  __syncthreads();
  if (wc == 0) {
    float linv[4];
#pragma unroll
    for (int r = 0; r < 4; ++r)
      linv[r] = 1.0f / (accL[r] + sL[wr * 16 + quad * 4 + r]);
#pragma unroll
    for (int t8 = 0; t8 < 8; ++t8)
#pragma unroll
      for (int r = 0; r < 4; ++r) {
        const int rl = wr * 16 + quad * 4 + r;
        float o = accO[t8][r] + sO[rl * 128 + t8 * 16 + l16];
        combined_bf[(size_t)(row0 + rl) * HID + (8 + hj) * DH + t8 * 16 + l16] =
            f2bf(o * linv[r]);
      }
  }
}

// ---------------------------------------------------------------------------
// Fused vanilla attention v3: same 2-blocks/CU structure as lyra_attn.
// grid (hj=8, by=64) with qt2 = by<32 ? by : 95-by so the two co-resident
// blocks on a CU (dispatched 256 apart) have qt2 summing to 63 -> constant
// per-CU causal work.  Split-precision QK (kh from LDS, ql and Klo residual
// in registers), raw p fp32 -> wout, exact shfl row-sums, PV from V-regs.
// vnorm finishes wout (normalize + zero upper triangle).
// ---------------------------------------------------------------------------
__global__ __launch_bounds__(256) void vanilla_attn(
    const float* __restrict__ qkv,
    const short* __restrict__ Kbf,   // hi keys: rows 2048.. of Kbf
    const short* __restrict__ Klo,   // [4][2048][128] residuals, same swizzle
    const short* __restrict__ Vtb,   // cols 2048.. are current v
    float* __restrict__ wout,
    float* __restrict__ vinv,        // [8][2048] 1/rowsum
    short* __restrict__ combined_bf) {
  __shared__ short sK[2][8192];
  __shared__ short sP[4][1024];
  __shared__ float sL[32];
  const int hj = blockIdx.x;
  const int by = blockIdx.y;
  const int qt2 = (by < 32) ? by : 95 - by;   // pair-balanced remap
  const int kvh = hj >> 1;
  const int t = threadIdx.x;
  const int w = t >> 6;
  const int lane = t & 63;
  const int quad = lane >> 4;
  const int l16 = lane & 15;
  const int wr = w >> 1;
  const int wc = w & 1;
  const int row0 = qt2 * 32;
  const int rbase = row0 + wr * 16 + quad * 4;
  const int swx = (l16 & 7) << 4;
  const int vsw = (l16 & 7) << 3;
  const int nt = qt2 / 2 + 1;        // 64-key tiles (causal)

  // q hi/lo fragments
  bf16x8 qh[4], ql[4];
  {
    const float* qrow =
        qkv + (size_t)(row0 + wr * 16 + l16) * QKV_W + hj * DH;
#pragma unroll
    for (int ks = 0; ks < 4; ++ks) {
#pragma unroll
      for (int e = 0; e < 8; ++e) {
        float x = qrow[ks * 32 + quad * 8 + e];
        short h = f2bf(x);
        qh[ks][e] = h;
        ql[ks][e] = f2bf(x - bf2f(h));
      }
    }
  }

  f32x4 accO[8];
#pragma unroll
  for (int i = 0; i < 8; ++i) accO[i] = (f32x4){0.f, 0.f, 0.f, 0.f};
  float accR[4] = {0.f, 0.f, 0.f, 0.f};

  const short* Kh = Kbf + ((size_t)kvh * 4096 + 2048) * DH;
  const short* Kl = Klo + (size_t)kvh * 2048 * DH;
  const short* Vb = Vtb + (size_t)kvh * DH * 4096 + 2048;  // current-v cols
  float* wrow = wout + (size_t)hj * S_LEN * S_LEN;

  stage_k64(Kh, &sK[0][0], 0, w, lane);

  short* sPw = &sP[w][0];
  int b = 0;
  for (int kt = 0; kt < nt; ++kt) {
    asm volatile("s_waitcnt vmcnt(0)" ::: "memory");
    __builtin_amdgcn_s_barrier();
    __builtin_amdgcn_sched_barrier(0);

    // register loads first (V + Klo residual), then staging GLDS
    bf16x8 bvg[8];
    const int vcol = kt * 64 + ((wc * 32 + quad * 8) ^ vsw);
#pragma unroll
    for (int t8 = 0; t8 < 8; ++t8)
      bvg[t8] = *(const bf16x8*)(Vb + (size_t)(t8 * 16 + l16) * 4096 + vcol);
    bf16x8 klf[2][4];
#pragma unroll
    for (int s = 0; s < 2; ++s)
#pragma unroll
      for (int ks = 0; ks < 4; ++ks)
        klf[s][ks] = *(const bf16x8*)(
            Kl + (size_t)(kt * 64 + wc * 32 + s * 16 + l16) * 128 +
            ((ks * 32 + quad * 8) ^ vsw));

    if (kt < nt - 1) stage_k64(Kh, &sK[b ^ 1][0], (kt + 1) * 64, w, lane);

    const char* Khs = (const char*)&sK[b][0];

    // split-precision QK^T
    f32x4 accS[2];
#pragma unroll
    for (int s = 0; s < 2; ++s) accS[s] = (f32x4){0.f, 0.f, 0.f, 0.f};
    __builtin_amdgcn_s_setprio(1);
#pragma unroll
    for (int s = 0; s < 2; ++s) {
      const char* krh = Khs + (wc * 32 + s * 16 + l16) * 256;
#pragma unroll
      for (int ks = 0; ks < 4; ++ks) {
        bf16x8 kh = *(const bf16x8*)(krh + ((ks * 64 + quad * 16) ^ swx));
        accS[s] = __builtin_amdgcn_mfma_f32_16x16x32_bf16(qh[ks], kh, accS[s], 0, 0, 0);
        accS[s] = __builtin_amdgcn_mfma_f32_16x16x32_bf16(ql[ks], kh, accS[s], 0, 0, 0);
        accS[s] = __builtin_amdgcn_mfma_f32_16x16x32_bf16(qh[ks], klf[s][ks], accS[s], 0, 0, 0);
      }
    }
    __builtin_amdgcn_s_setprio(0);

    // p = exp(s*SCALE - 12); causal zero on the diagonal tile; raw p -> wout
    const bool diag = (kt == nt - 1);
    float pr[4] = {0.f, 0.f, 0.f, 0.f};
#pragma unroll
    for (int s = 0; s < 2; ++s) {
      const int col = kt * 64 + wc * 32 + s * 16 + l16;
#pragma unroll
      for (int r = 0; r < 4; ++r) {
        const int row = quad * 4 + r;
        const int grow = rbase + r;
        float p = __expf(accS[s][r] * SCALE - LYRA_C);
        if (diag && col > grow) p = 0.f;
        pr[r] += p;
        const int sl = (s * 2 + (l16 >> 3)) ^ (row & 7);
        sPw[row * 64 + sl * 8 + (l16 & 7)] = f2bf(p);
        wrow[(size_t)grow * S_LEN + col] = p;
      }
    }
#pragma unroll
    for (int r = 0; r < 4; ++r) {
      float v = pr[r];
      v += __shfl_xor(v, 1);
      v += __shfl_xor(v, 2);
      v += __shfl_xor(v, 4);
      v += __shfl_xor(v, 8);
      accR[r] += v;
    }

    // PV from V-regs
    __builtin_amdgcn_s_setprio(1);
    bf16x8 ap = *(const bf16x8*)&sPw[l16 * 64 + ((quad ^ (l16 & 7)) << 3)];
#pragma unroll
    for (int t8 = 0; t8 < 8; ++t8)
      accO[t8] = __builtin_amdgcn_mfma_f32_16x16x32_bf16(ap, bvg[t8], accO[t8],
                                                         0, 0, 0);
    __builtin_amdgcn_s_setprio(0);

    b ^= 1;
  }

  // epilogue: merge 2 wc-partials; write normalized O and 1/rowsum.
  __syncthreads();
  float* sO = (float*)&sK[0][0];
  if (wc == 1) {
#pragma unroll
    for (int t8 = 0; t8 < 8; ++t8)
#pragma unroll
      for (int r = 0; r < 4; ++r)
        sO[(wr * 16 + quad * 4 + r) * 128 + t8 * 16 + l16] = accO[t8][r];
    if (l16 == 0) {
#pragma unroll
      for (int r = 0; r < 4; ++r) sL[wr * 16 + quad * 4 + r] = accR[r];
    }
  }
  __syncthreads();
  if (wc == 0) {
    float linv[4];
#pragma unroll
    for (int r = 0; r < 4; ++r)
      linv[r] = 1.0f / (accR[r] + sL[wr * 16 + quad * 4 + r]);
    if (l16 == 0) {
#pragma unroll
      for (int r = 0; r < 4; ++r)
        vinv[hj * S_LEN + rbase + r] = linv[r];
    }
#pragma unroll
    for (int t8 = 0; t8 < 8; ++t8)
#pragma unroll
      for (int r = 0; r < 4; ++r) {
        const int rl = wr * 16 + quad * 4 + r;
        float o = accO[t8][r] + sO[rl * 128 + t8 * 16 + l16];
        combined_bf[(size_t)(row0 + rl) * HID + hj * DH + t8 * 16 + l16] =
            f2bf(o * linv[r]);
      }
  }
}

// ---------------------------------------------------------------------------
// Normalize vanilla_w rows by stored 1/rowsum; zero-fill j > row.
// ---------------------------------------------------------------------------
__global__ __launch_bounds__(256) void vnorm(
    const float* __restrict__ vinv, float* __restrict__ wout) {
  const int row = blockIdx.x;
  const int h = blockIdx.y;
  float* p = wout + (size_t)h * S_LEN * S_LEN + (size_t)row * S_LEN;
  const float inv = vinv[h * S_LEN + row];
  const int t = threadIdx.x;
#pragma unroll
  for (int i = 0; i < 2; ++i) {
    const int j = (t + i * 256) * 4;
    float4 v;
    if (j > row) {
      v = make_float4(0.f, 0.f, 0.f, 0.f);
    } else if (j + 3 <= row) {
      v = *(const float4*)(p + j);
      v.x *= inv; v.y *= inv; v.z *= inv; v.w *= inv;
    } else {
      v = *(const float4*)(p + j);
      v.x = (j + 0 <= row) ? v.x * inv : 0.f;
      v.y = (j + 1 <= row) ? v.y * inv : 0.f;
      v.z = (j + 2 <= row) ? v.z * inv : 0.f;
      v.w = (j + 3 <= row) ? v.w * inv : 0.f;
    }
    *(float4*)(p + j) = v;
  }
}

// ---------------------------------------------------------------------------
extern "C" void kernel_launch(void* const* d_in, const int* in_sizes, int n_in,
                              void* d_out, int out_size, void* d_ws, size_t ws_size,
                              hipStream_t stream) {
  (void)in_sizes; (void)n_in; (void)out_size; (void)ws_size;
  const float* hidden = (const float*)d_in[0];
  const float* cosb   = (const float*)d_in[1];
  const float* sinb   = (const float*)d_in[2];
  const float* kcache = (const float*)d_in[4];
  const float* vcache = (const float*)d_in[5];
  const float* Wq = (const float*)d_in[6];
  const float* Wk = (const float*)d_in[7];
  const float* Wv = (const float*)d_in[8];
  const float* Wo = (const float*)d_in[9];
  const float* qw = (const float*)d_in[10];
  const float* kw = (const float*)d_in[11];

  float* out  = (float*)d_out;                     // attn_output [2048*2048]
  float* wout = out + (size_t)4194304;             // vanilla_w   [8*2048*2048]

  // d_ws: qkv f32 | Kbf | Vtb | combined_bf | Wo_bf
  float* qkv = (float*)d_ws;                       // [2048 x 3072] f32
  short* Kbf = (short*)(qkv + (size_t)2048 * QKV_W);
  short* Vtb = Kbf + (size_t)4 * 4096 * DH;
  short* combined_bf = Vtb + (size_t)4 * DH * 4096;   // [2048 x 2048] bf16
  short* Wo_bf = combined_bf + (size_t)2048 * HID;    // [2048 x 2048] bf16

  // transient scratch inside wout (consumed by gemm qkv before vanilla_attn
  // overwrites wout):
  short* hidden_bf = (short*)wout;                    // [2048 x 2048] bf16
  short* Wqkv_bf = hidden_bf + (size_t)2048 * HID;    // [3072 x 2048] bf16

  // transient scratch inside attn_output (dead before final gemm writes it):
  short* Klo  = (short*)out;                          // [4][2048][128] bf16 = 2 MB
  float* vinv = (float*)(Klo + (size_t)4 * 2048 * DH); // [8][2048] f32 = 64 KB

  pack_bf16<<<dim3(2048), 256, 0, stream>>>(hidden, hidden_bf);
  pack_bf16<<<dim3(2048), 256, 0, stream>>>(Wq, Wqkv_bf);
  pack_bf16<<<dim3(512), 256, 0, stream>>>(Wk, Wqkv_bf + (size_t)2048 * 2048);
  pack_bf16<<<dim3(512), 256, 0, stream>>>(Wv, Wqkv_bf + (size_t)2560 * 2048);
  pack_bf16<<<dim3(2048), 256, 0, stream>>>(Wo, Wo_bf);

  gemm_bf16<<<dim3(24, 16), 256, 0, stream>>>(hidden_bf, Wqkv_bf, qkv, 2048, QKV_W);
  rms_rope<<<dim3(10240), 256, 0, stream>>>(qkv, cosb, sinb, qw, kw);
  pack_k<<<dim3(2048), 256, 0, stream>>>(qkv, kcache, Kbf, Klo);
  pack_vt<<<dim3(64, 2, 4), 256, 0, stream>>>(qkv, vcache, Vtb);
  lyra_attn<<<dim3(8, 64), 256, 0, stream>>>(qkv, Kbf, Vtb, combined_bf);
  vanilla_attn<<<dim3(8, 64), 256, 0, stream>>>(qkv, Kbf, Klo, Vtb, wout, vinv,
                                                combined_bf);
  vnorm<<<dim3(2048, 8), 256, 0, stream>>>(vinv, wout);
  gemm_bf16<<<dim3(16, 16), 256, 0, stream>>>(combined_bf, Wo_bf, out, 2048, HID);
}

// Round 8
// 495.894 us; speedup vs baseline: 1.0802x; 1.0802x over previous
//
#include <hip/hip_runtime.h>
#include <math.h>

#define S_LEN 2048
#define HID 2048
#define NH 16
#define NKV 4
#define DH 128
#define CACHE_LEN 2048
#define QKV_W 3072   // q(2048) | k(512) | v(512) packed per row
#define SCALE 0.08838834764831845f
#define EPS 1e-6f
#define LYRA_C 12.0f // fixed softmax max-bound: |scores| <= ~19, exp(s-12) safe

typedef short bf16x8 __attribute__((ext_vector_type(8)));
typedef float f32x4 __attribute__((ext_vector_type(4)));

static __device__ __forceinline__ short f2bf(float x) {
  union { float f; unsigned u; } v; v.f = x;
  unsigned r = (v.u + 0x7FFF + ((v.u >> 16) & 1)) >> 16;
  return (short)r;
}

static __device__ __forceinline__ float bf2f(short h) {
  union { unsigned u; float f; } v;
  v.u = ((unsigned)(unsigned short)h) << 16;
  return v.f;
}

#define GLDS16(g, l)                                                      \
  __builtin_amdgcn_global_load_lds(                                       \
      (const __attribute__((address_space(1))) unsigned int*)(g),         \
      (__attribute__((address_space(3))) unsigned int*)(l), 16, 0, 0)

// ---------------------------------------------------------------------------
// fp32 -> bf16 pack, 8 elements/thread.
// ---------------------------------------------------------------------------
__global__ __launch_bounds__(256) void pack_bf16(
    const float* __restrict__ src, short* __restrict__ dst) {
  const int i = (blockIdx.x * 256 + threadIdx.x) * 8;
  float4 a = *(const float4*)(src + i);
  float4 b = *(const float4*)(src + i + 4);
  bf16x8 o;
  o[0] = f2bf(a.x); o[1] = f2bf(a.y); o[2] = f2bf(a.z); o[3] = f2bf(a.w);
  o[4] = f2bf(b.x); o[5] = f2bf(b.y); o[6] = f2bf(b.z); o[7] = f2bf(b.w);
  *(bf16x8*)(dst + i) = o;
}

// ---------------------------------------------------------------------------
// bf16 MFMA GEMM: C[M x N] fp32 = A[M x K]bf16 * B[N x K]bf16^T.
// ---------------------------------------------------------------------------
__global__ __launch_bounds__(256) void gemm_bf16(
    const short* __restrict__ A, const short* __restrict__ B,
    float* __restrict__ C, int K, int ldc) {
  __shared__ short sA[4096];
  __shared__ short sB[4096];
  const int t = threadIdx.x;
  const int w = t >> 6;
  const int lane = t & 63;
  const int quad = lane >> 4;
  const int l16 = lane & 15;
  const int tm = blockIdx.y * 128;
  const int tn = blockIdx.x * 128;
  const int srow = lane >> 2;
  const int scol = (lane & 3) * 8;
  const int mblk = (w & 1) * 64;
  const int nblk = (w >> 1) * 64;
  f32x4 acc[4][4];
#pragma unroll
  for (int i = 0; i < 4; ++i)
#pragma unroll
    for (int j = 0; j < 4; ++j) acc[i][j] = (f32x4){0.f, 0.f, 0.f, 0.f};

  const short* Ab = A + (size_t)(tm + w * 32 + srow) * K + scol;
  const short* Bb = B + (size_t)(tn + w * 32 + srow) * K + scol;
  const size_t rstep = (size_t)16 * K;

  for (int k0 = 0; k0 < K; k0 += 32) {
    GLDS16(Ab + k0, sA + (w * 2 + 0) * 512);
    GLDS16(Ab + rstep + k0, sA + (w * 2 + 1) * 512);
    GLDS16(Bb + k0, sB + (w * 2 + 0) * 512);
    GLDS16(Bb + rstep + k0, sB + (w * 2 + 1) * 512);
    __syncthreads();
    bf16x8 af[4], bfv[4];
#pragma unroll
  for (int ms = 0; ms < 4; ++ms)
      af[ms] = *(const bf16x8*)&sA[(mblk + ms * 16 + l16) * 32 + quad * 8];
#pragma unroll
    for (int ns = 0; ns < 4; ++ns)
      bfv[ns] = *(const bf16x8*)&sB[(nblk + ns * 16 + l16) * 32 + quad * 8];
#pragma unroll
    for (int ms = 0; ms < 4; ++ms)
#pragma unroll
      for (int ns = 0; ns < 4; ++ns)
        acc[ms][ns] = __builtin_amdgcn_mfma_f32_16x16x32_bf16(
            af[ms], bfv[ns], acc[ms][ns], 0, 0, 0);
    __syncthreads();
  }
#pragma unroll
  for (int ms = 0; ms < 4; ++ms)
#pragma unroll
    for (int ns = 0; ns < 4; ++ns) {
      const int row = tm + mblk + ms * 16 + quad * 4;
      const int col = tn + nblk + ns * 16 + l16;
#pragma unroll
      for (int r = 0; r < 4; ++r)
        C[(size_t)(row + r) * ldc + col] = acc[ms][ns][r];
    }
}

// ---------------------------------------------------------------------------
// RMSNorm(+1+w) then RoPE, in-place on q (16 heads) and k (4 heads).
// ---------------------------------------------------------------------------
__global__ __launch_bounds__(256) void rms_rope(
    float* __restrict__ qkv,
    const float* __restrict__ cosb, const float* __restrict__ sinb,
    const float* __restrict__ qw, const float* __restrict__ kw) {
  const int unit = blockIdx.x * 4 + (threadIdx.x >> 6);
  const int lane = threadIdx.x & 63;
  const int total_q = S_LEN * NH;
  float* base;
  const float* w;
  int pos;
  if (unit < total_q) {
    pos = unit >> 4;
    int head = unit & 15;
    base = qkv + (size_t)pos * QKV_W + head * DH;
    w = qw;
  } else {
    int u = unit - total_q;
    pos = u >> 2;
    int head = u & 3;
    base = qkv + (size_t)pos * QKV_W + 2048 + head * DH;
    w = kw;
  }
  float x0 = base[lane];
  float x1 = base[lane + 64];
  float ss = x0 * x0 + x1 * x1;
#pragma unroll
  for (int off = 32; off > 0; off >>= 1) ss += __shfl_xor(ss, off);
  float r = rsqrtf(ss * (1.0f / 128.0f) + EPS);
  float n0 = x0 * r * (1.0f + w[lane]);
  float n1 = x1 * r * (1.0f + w[lane + 64]);
  float c0 = cosb[(size_t)pos * DH + lane];
  float c1 = cosb[(size_t)pos * DH + lane + 64];
  float s0 = sinb[(size_t)pos * DH + lane];
  float s1 = sinb[(size_t)pos * DH + lane + 64];
  base[lane]      = n0 * c0 - n1 * s0;
  base[lane + 64] = n1 * c1 + n0 * s1;
}

// ---------------------------------------------------------------------------
// Pack K (cache ++ roped k) -> bf16 Kbf[4][4096][128], PRE-SWIZZLED within
// each 128-elem row: element d stored at d ^ ((key&7)<<3).  For current keys
// (>= CACHE_LEN) also emit the bf16 residual (lo = x - bf16(x)) to Klo
// [4][2048][128], same swizzle — used by vanilla_attn's split-precision QK.
// ---------------------------------------------------------------------------
__global__ __launch_bounds__(256) void pack_k(
    const float* __restrict__ qkv, const float* __restrict__ kcache,
    short* __restrict__ Kbf, short* __restrict__ Klo) {
  const int idx = blockIdx.x * 256 + threadIdx.x;
  const int e4 = idx * 4;
  const int kvh = e4 >> 19;
  const int rem = e4 & ((1 << 19) - 1);
  const int key = rem >> 7;
  const int d = rem & 127;
  const int dsw = d ^ ((key & 7) << 3);       // in-row XOR swizzle (8-elem units)
  if (key < CACHE_LEN) {
    float4 v = *(const float4*)(kcache + (((size_t)kvh * CACHE_LEN + key) << 7) + d);
    short4 o;
    o.x = f2bf(v.x); o.y = f2bf(v.y); o.z = f2bf(v.z); o.w = f2bf(v.w);
    *(short4*)(Kbf + (size_t)(e4 - d) + dsw) = o;
  } else {
    float4 v = *(const float4*)(qkv + (size_t)(key - CACHE_LEN) * QKV_W + 2048 + kvh * DH + d);
    short4 o;
    o.x = f2bf(v.x); o.y = f2bf(v.y); o.z = f2bf(v.z); o.w = f2bf(v.w);
    *(short4*)(Kbf + (size_t)(e4 - d) + dsw) = o;
    short4 ol;
    ol.x = f2bf(v.x - bf2f(o.x));
    ol.y = f2bf(v.y - bf2f(o.y));
    ol.z = f2bf(v.z - bf2f(o.z));
    ol.w = f2bf(v.w - bf2f(o.w));
    *(short4*)(Klo + ((size_t)kvh * 2048 + (key - CACHE_LEN)) * 128 + dsw) = ol;
  }
}

// ---------------------------------------------------------------------------
// Pack V transposed -> bf16 Vt[4][128][4096], PRE-SWIZZLED within each
// 64-key chunk: key c stored at c ^ ((d&7)<<3).
// ---------------------------------------------------------------------------
__global__ __launch_bounds__(256) void pack_vt(
    const float* __restrict__ qkv, const float* __restrict__ vcache,
    short* __restrict__ Vt) {
  __shared__ float tile[64][65];
  const int key0 = blockIdx.x * 64;
  const int d0 = blockIdx.y * 64;
  const int kvh = blockIdx.z;
  const int t = threadIdx.x;
  const int c = t & 63;
  const int r0 = t >> 6;
#pragma unroll
  for (int i = 0; i < 16; ++i) {
    int r = r0 + i * 4;
    int key = key0 + r;
    float v;
    if (key < CACHE_LEN)
      v = vcache[(((size_t)kvh * CACHE_LEN + key) << 7) + d0 + c];
    else
      v = qkv[(size_t)(key - CACHE_LEN) * QKV_W + 2560 + kvh * DH + d0 + c];
    tile[r][c] = v;
  }
  __syncthreads();
#pragma unroll
  for (int i = 0; i < 16; ++i) {
    int wr = r0 + i * 4;
    int csw = c ^ (((d0 + wr) & 7) << 3);     // in-chunk XOR swizzle
    Vt[((size_t)kvh * DH + d0 + wr) * 4096 + key0 + csw] = f2bf(tile[c][wr]);
  }
}

// ---------------------------------------------------------------------------
// Stage one 128-key K/V tile into an LDS buffer via global_load_lds (16B).
// Per wave: 4 GLDS for K (16 key-rows x 256B) + 4 GLDS for V (16 d-rows x
// 256B).  Global layouts are pre-swizzled, LDS dests linear (rule 21).
// buf layout (shorts): [0..16383]=K(key*128+e), [16384..32767]=Vt(d*128+key)
// ---------------------------------------------------------------------------
static __device__ __forceinline__ void stage_kv128(
    const short* Kb, const short* Vb, short* buf, int key0, int w, int lane) {
#pragma unroll
  for (int i = 0; i < 4; ++i)
    GLDS16(Kb + ((size_t)key0 + w * 16 + i * 4) * 128 + lane * 8,
           buf + (w * 16 + i * 4) * 128);
#pragma unroll
  for (int i = 0; i < 4; ++i)
    GLDS16(Vb + (size_t)(w * 16 + i * 4 + (lane >> 4)) * 4096 + key0 +
               (lane & 15) * 8,
           buf + 16384 + (w * 16 + i * 4) * 128);
}

// ---------------------------------------------------------------------------
// Lyra attention (R4-verified structure + softmax diet): 8 waves = 2
// row-waves (32 rows = 2 MFMA groups) x 4 key-waves (32 keys of a 128-key
// tile).  Each K/V LDS read feeds 2 MFMAs.  Double-buffered 64KB K/V
// staging, one barrier per 128-key tile.  sP per-wave [2 groups][16][64]
// with slot^(row&7) XOR.  Epilogue merges 4 wc-partials through the dead
// K/V buffers.  Diet: q pre-scaled by SCALE (bf16 rel-error is scale
// invariant), MFMA C-init = -LYRA_C, p = exp(acc) directly.
// Grid (hj=8, qt=32): id%8==hj pins each kvh to one XCD L2.
// ---------------------------------------------------------------------------
__global__ __launch_bounds__(512) void lyra_attn(
    const float* __restrict__ qkv,
    const short* __restrict__ Kbf,   // [4][4096][128] pre-swizzled rows
    const short* __restrict__ Vtb,   // [4][128][4096] pre-swizzled 64-chunks
    short* __restrict__ combined_bf) {
  __shared__ short sKV[2][32768];    // 2 x (K 32KB | Vt 32KB)
  __shared__ short sP[8][2][1024];   // per-wave, per-group [16][64]
  const int hj = blockIdx.x;
  const int qt = blockIdx.y;
  const int kvh = hj >> 1;
  const int t = threadIdx.x;
  const int w = t >> 6;
  const int lane = t & 63;
  const int quad = lane >> 4;
  const int l16 = lane & 15;
  const int wr = w >> 2;             // 0..1 : 32 rows
  const int wc = w & 3;              // 0..3 : 32-key slice of 128
  const int row0 = qt * 64;
  const int swx = (l16 & 7) << 4;    // byte XOR for swizzled ds_read_b128
  // V byte offset within a 256B d-row for this wave's 32 keys:
  const int voff = (wc >> 1) * 128 + ((((wc & 1) * 64) + quad * 16) ^ swx);

  // q fragments: 2 row-groups x 4 k-slices, pre-scaled by SCALE
  bf16x8 qf[2][4];
#pragma unroll
  for (int g = 0; g < 2; ++g) {
    const float* qrow =
        qkv + (size_t)(row0 + wr * 32 + g * 16 + l16) * QKV_W + (8 + hj) * DH;
#pragma unroll
    for (int ks = 0; ks < 4; ++ks) {
      float4 f0 = *(const float4*)(qrow + ks * 32 + quad * 8);
      float4 f1 = *(const float4*)(qrow + ks * 32 + quad * 8 + 4);
      qf[g][ks][0] = f2bf(f0.x * SCALE); qf[g][ks][1] = f2bf(f0.y * SCALE);
      qf[g][ks][2] = f2bf(f0.z * SCALE); qf[g][ks][3] = f2bf(f0.w * SCALE);
      qf[g][ks][4] = f2bf(f1.x * SCALE); qf[g][ks][5] = f2bf(f1.y * SCALE);
      qf[g][ks][6] = f2bf(f1.z * SCALE); qf[g][ks][7] = f2bf(f1.w * SCALE);
    }
  }
  bf16x8 onesf;
#pragma unroll
  for (int i = 0; i < 8; ++i) onesf[i] = (short)0x3F80;  // bf16 1.0

  f32x4 accO[2][8];
#pragma unroll
  for (int g = 0; g < 2; ++g)
#pragma unroll
    for (int i = 0; i < 8; ++i) accO[g][i] = (f32x4){0.f, 0.f, 0.f, 0.f};
  f32x4 accL[2];
  accL[0] = (f32x4){0.f, 0.f, 0.f, 0.f};
  accL[1] = (f32x4){0.f, 0.f, 0.f, 0.f};

  const short* Kb = Kbf + (size_t)kvh * 4096 * DH;
  const short* Vb = Vtb + (size_t)kvh * DH * 4096;

  stage_kv128(Kb, Vb, &sKV[0][0], 0, w, lane);

  int b = 0;
  for (int kt = 0; kt < 32; ++kt) {
    asm volatile("s_waitcnt vmcnt(0)" ::: "memory");
    __builtin_amdgcn_s_barrier();
    __builtin_amdgcn_sched_barrier(0);

    if (kt < 31)
      stage_kv128(Kb, Vb, &sKV[b ^ 1][0], (kt + 1) * 128, w, lane);

    const char* Ksc = (const char*)&sKV[b][0];
    const char* Vsc = (const char*)&sKV[b][16384];

    // QK^T with C-init = -LYRA_C; each bk read feeds both row-groups.
    f32x4 accS[2][2];
#pragma unroll
    for (int g = 0; g < 2; ++g)
#pragma unroll
      for (int s = 0; s < 2; ++s)
        accS[g][s] = (f32x4){-LYRA_C, -LYRA_C, -LYRA_C, -LYRA_C};
    __builtin_amdgcn_s_setprio(1);
#pragma unroll
    for (int s = 0; s < 2; ++s) {
      const char* krow = Ksc + (wc * 32 + s * 16 + l16) * 256;
#pragma unroll
      for (int ks = 0; ks < 4; ++ks) {
        bf16x8 bk = *(const bf16x8*)(krow + ((ks * 64 + quad * 16) ^ swx));
        accS[0][s] = __builtin_amdgcn_mfma_f32_16x16x32_bf16(qf[0][ks], bk, accS[0][s], 0, 0, 0);
        accS[1][s] = __builtin_amdgcn_mfma_f32_16x16x32_bf16(qf[1][ks], bk, accS[1][s], 0, 0, 0);
      }
    }
    __builtin_amdgcn_s_setprio(0);

    // p = exp(acc) (acc = s*SCALE - 12 already); mask (+1.0) iff
    // col - CACHE_LEN > row (false automatically for cached keys).
    const int base = kt * 128 + wc * 32;
#pragma unroll
    for (int g = 0; g < 2; ++g) {
      short* sPg = &sP[w][g][0];
#pragma unroll
      for (int s = 0; s < 2; ++s) {
        const int col = base + s * 16 + l16;
#pragma unroll
        for (int r = 0; r < 4; ++r) {
          const int row = quad * 4 + r;
          const int grow = row0 + wr * 32 + g * 16 + row;
          float z = accS[g][s][r];
          if ((col - CACHE_LEN) > grow) z += 1.0f;
          const int sl = (s * 2 + (l16 >> 3)) ^ (row & 7);
          sPg[row * 64 + sl * 8 + (l16 & 7)] = f2bf(__expf(z));
        }
      }
    }

    // PV + row-sum; each bv read feeds both row-groups.
    __builtin_amdgcn_s_setprio(1);
    bf16x8 ap0 = *(const bf16x8*)&sP[w][0][l16 * 64 + ((quad ^ (l16 & 7)) << 3)];
    bf16x8 ap1 = *(const bf16x8*)&sP[w][1][l16 * 64 + ((quad ^ (l16 & 7)) << 3)];
    accL[0] = __builtin_amdgcn_mfma_f32_16x16x32_bf16(ap0, onesf, accL[0], 0, 0, 0);
    accL[1] = __builtin_amdgcn_mfma_f32_16x16x32_bf16(ap1, onesf, accL[1], 0, 0, 0);
#pragma unroll
    for (int t8 = 0; t8 < 8; ++t8) {
      bf16x8 bv = *(const bf16x8*)(Vsc + (t8 * 16 + l16) * 256 + voff);
      accO[0][t8] = __builtin_amdgcn_mfma_f32_16x16x32_bf16(ap0, bv, accO[0][t8], 0, 0, 0);
      accO[1][t8] = __builtin_amdgcn_mfma_f32_16x16x32_bf16(ap1, bv, accO[1][t8], 0, 0, 0);
    }
    __builtin_amdgcn_s_setprio(0);

    b ^= 1;
  }

  // epilogue: merge 4 wc-partials (wc 1..3 via 96KB of dead sKV + sL in sP),
  // normalize, write bf16 output.
  __syncthreads();
  float* sO = (float*)&sKV[0][0];
  float* sLa = (float*)&sP[0][0][0];  // [3][64]
  if (wc != 0) {
    float* dst = sO + (size_t)(wc - 1) * 8192;
#pragma unroll
    for (int g = 0; g < 2; ++g)
#pragma unroll
      for (int t8 = 0; t8 < 8; ++t8)
#pragma unroll
        for (int r = 0; r < 4; ++r) {
          const int rl = wr * 32 + g * 16 + quad * 4 + r;
          dst[rl * 128 + t8 * 16 + l16] = accO[g][t8][r];
        }
    if (l16 == 0) {
#pragma unroll
      for (int g = 0; g < 2; ++g)
#pragma unroll
        for (int r = 0; r < 4; ++r)
          sLa[(wc - 1) * 64 + wr * 32 + g * 16 + quad * 4 + r] = accL[g][r];
    }
  }
  __syncthreads();
  if (wc == 0) {
#pragma unroll
    for (int g = 0; g < 2; ++g) {
      float linv[4];
#pragma unroll
      for (int r = 0; r < 4; ++r) {
        const int rl = wr * 32 + g * 16 + quad * 4 + r;
        linv[r] = 1.0f / (accL[g][r] + sLa[rl] + sLa[64 + rl] + sLa[128 + rl]);
      }
#pragma unroll
      for (int t8 = 0; t8 < 8; ++t8)
#pragma unroll
        for (int r = 0; r < 4; ++r) {
          const int rl = wr * 32 + g * 16 + quad * 4 + r;
          const int c = t8 * 16 + l16;
          float o = accO[g][t8][r] + sO[rl * 128 + c] + sO[8192 + rl * 128 + c] +
                    sO[16384 + rl * 128 + c];
          combined_bf[(size_t)(row0 + rl) * HID + (8 + hj) * DH + c] =
              f2bf(o * linv[r]);
        }
    }
  }
}

// ---------------------------------------------------------------------------
// Fused vanilla attention (R4-verified structure + softmax diet): 2 row-waves
// x 4 key-waves, 128-key tiles (worst block 17 tiles).  Split-precision QK:
// kh from LDS, kl (residual) from L2-resident Klo straight into registers.
// q pre-scaled by SCALE, C-init = -LYRA_C, p = exp(acc) fp32 -> raw to wout;
// exact shfl row-sums; PV bf16.  Epilogue merges 4 wc-partials, writes
// normalized O and 1/rowsum (vnorm finishes wout).
// ---------------------------------------------------------------------------
__global__ __launch_bounds__(512) void vanilla_attn(
    const float* __restrict__ qkv,
    const short* __restrict__ Kbf,   // hi keys: rows 2048.. of Kbf
    const short* __restrict__ Klo,   // [4][2048][128] residuals, same swizzle
    const short* __restrict__ Vtb,   // cols 2048.. are current v
    float* __restrict__ wout,
    float* __restrict__ vinv,        // [8][2048] 1/rowsum
    short* __restrict__ combined_bf) {
  __shared__ short sKV[2][32768];    // 2 x (Khi 32KB | Vt 32KB)
  __shared__ short sP[8][2][1024];
  const int hj = blockIdx.x;
  const int qt = blockIdx.y;
  const int kvh = hj >> 1;
  const int t = threadIdx.x;
  const int w = t >> 6;
  const int lane = t & 63;
  const int quad = lane >> 4;
  const int l16 = lane & 15;
  const int wr = w >> 2;
  const int wc = w & 3;
  const int row0 = qt * 64;
  const int swx = (l16 & 7) << 4;
  const int voff = (wc >> 1) * 128 + ((((wc & 1) * 64) + quad * 16) ^ swx);
  const int nt = qt / 2 + 1;         // number of 128-key tiles (causal)

  // q hi/lo fragments from fp32, pre-scaled by SCALE
  bf16x8 qh[2][4], ql[2][4];
#pragma unroll
  for (int g = 0; g < 2; ++g) {
    const float* qrow =
        qkv + (size_t)(row0 + wr * 32 + g * 16 + l16) * QKV_W + hj * DH;
#pragma unroll
    for (int ks = 0; ks < 4; ++ks) {
#pragma unroll
      for (int e = 0; e < 8; ++e) {
        float x = qrow[ks * 32 + quad * 8 + e] * SCALE;
        short h = f2bf(x);
        qh[g][ks][e] = h;
        ql[g][ks][e] = f2bf(x - bf2f(h));
      }
    }
  }

  f32x4 accO[2][8];
#pragma unroll
  for (int g = 0; g < 2; ++g)
#pragma unroll
    for (int i = 0; i < 8; ++i) accO[g][i] = (f32x4){0.f, 0.f, 0.f, 0.f};
  float accR[2][4] = {{0.f, 0.f, 0.f, 0.f}, {0.f, 0.f, 0.f, 0.f}};

  const short* Kh = Kbf + ((size_t)kvh * 4096 + 2048) * DH;
  const short* Kl = Klo + (size_t)kvh * 2048 * DH;
  const short* Vb = Vtb + (size_t)kvh * DH * 4096 + 2048;  // current-v cols
  float* wrow = wout + (size_t)hj * S_LEN * S_LEN;

  stage_kv128(Kh, Vb, &sKV[0][0], 0, w, lane);

  int b = 0;
  for (int kt = 0; kt < nt; ++kt) {
    asm volatile("s_waitcnt vmcnt(0)" ::: "memory");
    __builtin_amdgcn_s_barrier();
    __builtin_amdgcn_sched_barrier(0);

    if (kt < nt - 1)
      stage_kv128(Kh, Vb, &sKV[b ^ 1][0], (kt + 1) * 128, w, lane);

    const int key0 = kt * 128;
    // kl residuals for this wave's 32 keys: per-lane L2 loads into regs
    bf16x8 klf[2][4];
#pragma unroll
    for (int s = 0; s < 2; ++s)
#pragma unroll
      for (int ks = 0; ks < 4; ++ks)
        klf[s][ks] = *(const bf16x8*)(
            Kl + (size_t)(key0 + wc * 32 + s * 16 + l16) * 128 +
            ((ks * 32 + quad * 8) ^ ((l16 & 7) << 3)));

    const char* Khs = (const char*)&sKV[b][0];
    const char* Vsc = (const char*)&sKV[b][16384];

    f32x4 accS[2][2];
#pragma unroll
    for (int g = 0; g < 2; ++g)
#pragma unroll
      for (int s = 0; s < 2; ++s)
        accS[g][s] = (f32x4){-LYRA_C, -LYRA_C, -LYRA_C, -LYRA_C};
    __builtin_amdgcn_s_setprio(1);
#pragma unroll
    for (int s = 0; s < 2; ++s) {
      const char* krh = Khs + (wc * 32 + s * 16 + l16) * 256;
#pragma unroll
      for (int ks = 0; ks < 4; ++ks) {
        bf16x8 kh = *(const bf16x8*)(krh + ((ks * 64 + quad * 16) ^ swx));
        accS[0][s] = __builtin_amdgcn_mfma_f32_16x16x32_bf16(qh[0][ks], kh, accS[0][s], 0, 0, 0);
        accS[1][s] = __builtin_amdgcn_mfma_f32_16x16x32_bf16(qh[1][ks], kh, accS[1][s], 0, 0, 0);
        accS[0][s] = __builtin_amdgcn_mfma_f32_16x16x32_bf16(ql[0][ks], kh, accS[0][s], 0, 0, 0);
        accS[1][s] = __builtin_amdgcn_mfma_f32_16x16x32_bf16(ql[1][ks], kh, accS[1][s], 0, 0, 0);
        accS[0][s] = __builtin_amdgcn_mfma_f32_16x16x32_bf16(qh[0][ks], klf[s][ks], accS[0][s], 0, 0, 0);
        accS[1][s] = __builtin_amdgcn_mfma_f32_16x16x32_bf16(qh[1][ks], klf[s][ks], accS[1][s], 0, 0, 0);
      }
    }
    __builtin_amdgcn_s_setprio(0);

    // p = exp(acc); causal zero on the diagonal tile; raw p -> wout
    const bool diag = (kt == nt - 1);
#pragma unroll
    for (int g = 0; g < 2; ++g) {
      short* sPg = &sP[w][g][0];
      float pr[4] = {0.f, 0.f, 0.f, 0.f};
#pragma unroll
      for (int s = 0; s < 2; ++s) {
        const int col = key0 + wc * 32 + s * 16 + l16;
#pragma unroll
        for (int r = 0; r < 4; ++r) {
          const int row = quad * 4 + r;
          const int grow = row0 + wr * 32 + g * 16 + row;
          float p = __expf(accS[g][s][r]);
          if (diag && col > grow) p = 0.f;
          pr[r] += p;
          const int sl = (s * 2 + (l16 >> 3)) ^ (row & 7);
          sPg[row * 64 + sl * 8 + (l16 & 7)] = f2bf(p);
          wrow[(size_t)grow * S_LEN + col] = p;
        }
      }
#pragma unroll
      for (int r = 0; r < 4; ++r) {
        float v = pr[r];
        v += __shfl_xor(v, 1);
        v += __shfl_xor(v, 2);
        v += __shfl_xor(v, 4);
        v += __shfl_xor(v, 8);
        accR[g][r] += v;
      }
    }

    // PV over this wave's 32-key slice
    __builtin_amdgcn_s_setprio(1);
    bf16x8 ap0 = *(const bf16x8*)&sP[w][0][l16 * 64 + ((quad ^ (l16 & 7)) << 3)];
    bf16x8 ap1 = *(const bf16x8*)&sP[w][1][l16 * 64 + ((quad ^ (l16 & 7)) << 3)];
#pragma unroll
    for (int t8 = 0; t8 < 8; ++t8) {
      bf16x8 bv = *(const bf16x8*)(Vsc + (t8 * 16 + l16) * 256 + voff);
      accO[0][t8] = __builtin_amdgcn_mfma_f32_16x16x32_bf16(ap0, bv, accO[0][t8], 0, 0, 0);
      accO[1][t8] = __builtin_amdgcn_mfma_f32_16x16x32_bf16(ap1, bv, accO[1][t8], 0, 0, 0);
    }
    __builtin_amdgcn_s_setprio(0);

    b ^= 1;
  }

  // epilogue: merge 4 wc-partials; write normalized O and 1/rowsum.
  __syncthreads();
  float* sO = (float*)&sKV[0][0];
  float* sLa = (float*)&sP[0][0][0];  // [3][64]
  if (wc != 0) {
    float* dst = sO + (size_t)(wc - 1) * 8192;
#pragma unroll
    for (int g = 0; g < 2; ++g)
#pragma unroll
      for (int t8 = 0; t8 < 8; ++t8)
#pragma unroll
        for (int r = 0; r < 4; ++r) {
          const int rl = wr * 32 + g * 16 + quad * 4 + r;
          dst[rl * 128 + t8 * 16 + l16] = accO[g][t8][r];
        }
    if (l16 == 0) {
#pragma unroll
      for (int g = 0; g < 2; ++g)
#pragma unroll
        for (int r = 0; r < 4; ++r)
          sLa[(wc - 1) * 64 + wr * 32 + g * 16 + quad * 4 + r] = accR[g][r];
    }
  }
  __syncthreads();
  if (wc == 0) {
#pragma unroll
    for (int g = 0; g < 2; ++g) {
      float linv[4];
#pragma unroll
      for (int r = 0; r < 4; ++r) {
        const int rl = wr * 32 + g * 16 + quad * 4 + r;
        linv[r] = 1.0f / (accR[g][r] + sLa[rl] + sLa[64 + rl] + sLa[128 + rl]);
      }
      if (l16 == 0) {
#pragma unroll
        for (int r = 0; r < 4; ++r)
          vinv[hj * S_LEN + row0 + wr * 32 + g * 16 + quad * 4 + r] = linv[r];
      }
#pragma unroll
      for (int t8 = 0; t8 < 8; ++t8)
#pragma unroll
        for (int r = 0; r < 4; ++r) {
          const int rl = wr * 32 + g * 16 + quad * 4 + r;
          const int c = t8 * 16 + l16;
          float o = accO[g][t8][r] + sO[rl * 128 + c] + sO[8192 + rl * 128 + c] +
                    sO[16384 + rl * 128 + c];
          combined_bf[(size_t)(row0 + rl) * HID + hj * DH + c] =
              f2bf(o * linv[r]);
        }
    }
  }
}

// ---------------------------------------------------------------------------
// Normalize vanilla_w rows by stored 1/rowsum; zero-fill j > row.
// ---------------------------------------------------------------------------
__global__ __launch_bounds__(256) void vnorm(
    const float* __restrict__ vinv, float* __restrict__ wout) {
  const int row = blockIdx.x;
  const int h = blockIdx.y;
  float* p = wout + (size_t)h * S_LEN * S_LEN + (size_t)row * S_LEN;
  const float inv = vinv[h * S_LEN + row];
  const int t = threadIdx.x;
#pragma unroll
  for (int i = 0; i < 2; ++i) {
    const int j = (t + i * 256) * 4;
    float4 v;
    if (j > row) {
      v = make_float4(0.f, 0.f, 0.f, 0.f);
    } else if (j + 3 <= row) {
      v = *(const float4*)(p + j);
      v.x *= inv; v.y *= inv; v.z *= inv; v.w *= inv;
    } else {
      v = *(const float4*)(p + j);
      v.x = (j + 0 <= row) ? v.x * inv : 0.f;
      v.y = (j + 1 <= row) ? v.y * inv : 0.f;
      v.z = (j + 2 <= row) ? v.z * inv : 0.f;
      v.w = (j + 3 <= row) ? v.w * inv : 0.f;
    }
    *(float4*)(p + j) = v;
  }
}

// ---------------------------------------------------------------------------
extern "C" void kernel_launch(void* const* d_in, const int* in_sizes, int n_in,
                              void* d_out, int out_size, void* d_ws, size_t ws_size,
                              hipStream_t stream) {
  (void)in_sizes; (void)n_in; (void)out_size; (void)ws_size;
  const float* hidden = (const float*)d_in[0];
  const float* cosb   = (const float*)d_in[1];
  const float* sinb   = (const float*)d_in[2];
  const float* kcache = (const float*)d_in[4];
  const float* vcache = (const float*)d_in[5];
  const float* Wq = (const float*)d_in[6];
  const float* Wk = (const float*)d_in[7];
  const float* Wv = (const float*)d_in[8];
  const float* Wo = (const float*)d_in[9];
  const float* qw = (const float*)d_in[10];
  const float* kw = (const float*)d_in[11];

  float* out  = (float*)d_out;                     // attn_output [2048*2048]
  float* wout = out + (size_t)4194304;             // vanilla_w   [8*2048*2048]

  // d_ws: qkv f32 | Kbf | Vtb | combined_bf | Wo_bf
  float* qkv = (float*)d_ws;                       // [2048 x 3072] f32
  short* Kbf = (short*)(qkv + (size_t)2048 * QKV_W);
  short* Vtb = Kbf + (size_t)4 * 4096 * DH;
  short* combined_bf = Vtb + (size_t)4 * DH * 4096;   // [2048 x 2048] bf16
  short* Wo_bf = combined_bf + (size_t)2048 * HID;    // [2048 x 2048] bf16

  // transient scratch inside wout (consumed by gemm qkv before vanilla_attn
  // overwrites wout):
  short* hidden_bf = (short*)wout;                    // [2048 x 2048] bf16
  short* Wqkv_bf = hidden_bf + (size_t)2048 * HID;    // [3072 x 2048] bf16

  // transient scratch inside attn_output (dead before final gemm writes it):
  short* Klo  = (short*)out;                          // [4][2048][128] bf16 = 2 MB
  float* vinv = (float*)(Klo + (size_t)4 * 2048 * DH); // [8][2048] f32 = 64 KB

  pack_bf16<<<dim3(2048), 256, 0, stream>>>(hidden, hidden_bf);
  pack_bf16<<<dim3(2048), 256, 0, stream>>>(Wq, Wqkv_bf);
  pack_bf16<<<dim3(512), 256, 0, stream>>>(Wk, Wqkv_bf + (size_t)2048 * 2048);
  pack_bf16<<<dim3(512), 256, 0, stream>>>(Wv, Wqkv_bf + (size_t)2560 * 2048);
  pack_bf16<<<dim3(2048), 256, 0, stream>>>(Wo, Wo_bf);

  gemm_bf16<<<dim3(24, 16), 256, 0, stream>>>(hidden_bf, Wqkv_bf, qkv, 2048, QKV_W);
  rms_rope<<<dim3(10240), 256, 0, stream>>>(qkv, cosb, sinb, qw, kw);
  pack_k<<<dim3(2048), 256, 0, stream>>>(qkv, kcache, Kbf, Klo);
  pack_vt<<<dim3(64, 2, 4), 256, 0, stream>>>(qkv, vcache, Vtb);
  lyra_attn<<<dim3(8, 32), 512, 0, stream>>>(qkv, Kbf, Vtb, combined_bf);
  vanilla_attn<<<dim3(8, 32), 512, 0, stream>>>(qkv, Kbf, Klo, Vtb, wout, vinv,
                                                combined_bf);
  vnorm<<<dim3(2048, 8), 256, 0, stream>>>(vinv, wout);
  gemm_bf16<<<dim3(16, 16), 256, 0, stream>>>(combined_bf, Wo_bf, out, 2048, HID);
}

// Round 9
// 476.216 us; speedup vs baseline: 1.1248x; 1.0413x over previous
//
#include <hip/hip_runtime.h>
#include <math.h>

#define S_LEN 2048
#define HID 2048
#define NH 16
#define NKV 4
#define DH 128
#define CACHE_LEN 2048
#define QKV_W 3072   // q(2048) | k(512) | v(512) packed per row
#define SCALE 0.08838834764831845f
#define EPS 1e-6f
#define LYRA_C 12.0f // fixed softmax max-bound: |scores| <= ~19, exp(s-12) safe

typedef short bf16x8 __attribute__((ext_vector_type(8)));
typedef float f32x4 __attribute__((ext_vector_type(4)));

static __device__ __forceinline__ short f2bf(float x) {
  union { float f; unsigned u; } v; v.f = x;
  unsigned r = (v.u + 0x7FFF + ((v.u >> 16) & 1)) >> 16;
  return (short)r;
}

static __device__ __forceinline__ float bf2f(short h) {
  union { unsigned u; float f; } v;
  v.u = ((unsigned)(unsigned short)h) << 16;
  return v.f;
}

#define GLDS16(g, l)                                                      \
  __builtin_amdgcn_global_load_lds(                                       \
      (const __attribute__((address_space(1))) unsigned int*)(g),         \
      (__attribute__((address_space(3))) unsigned int*)(l), 16, 0, 0)

// ---------------------------------------------------------------------------
// Fused fp32 -> bf16 pack of hidden, Wq, Wk, Wv, Wo (one launch).
// Block ranges: [0,2048) hidden | [2048,4096) Wq | [4096,4608) Wk |
// [4608,5120) Wv | [5120,7168) Wo.  8 elements/thread.
// ---------------------------------------------------------------------------
__global__ __launch_bounds__(256) void pack_all(
    const float* __restrict__ hidden, const float* __restrict__ Wq,
    const float* __restrict__ Wk, const float* __restrict__ Wv,
    const float* __restrict__ Wo, short* __restrict__ hidden_bf,
    short* __restrict__ Wqkv_bf, short* __restrict__ Wo_bf) {
  const int b = blockIdx.x;
  const float* src;
  short* dst;
  int off;
  if (b < 2048)      { src = hidden; dst = hidden_bf; off = b; }
  else if (b < 4096) { src = Wq; dst = Wqkv_bf; off = b - 2048; }
  else if (b < 4608) { src = Wk; dst = Wqkv_bf + (size_t)2048 * 2048; off = b - 4096; }
  else if (b < 5120) { src = Wv; dst = Wqkv_bf + (size_t)2560 * 2048; off = b - 4608; }
  else               { src = Wo; dst = Wo_bf; off = b - 5120; }
  const int i = (off * 256 + threadIdx.x) * 8;
  float4 a = *(const float4*)(src + i);
  float4 c = *(const float4*)(src + i + 4);
  bf16x8 o;
  o[0] = f2bf(a.x); o[1] = f2bf(a.y); o[2] = f2bf(a.z); o[3] = f2bf(a.w);
  o[4] = f2bf(c.x); o[5] = f2bf(c.y); o[6] = f2bf(c.z); o[7] = f2bf(c.w);
  *(bf16x8*)(dst + i) = o;
}

// ---------------------------------------------------------------------------
// bf16 MFMA GEMM: C[M x N] fp32 = A[M x K]bf16 * B[N x K]bf16^T.
// ---------------------------------------------------------------------------
__global__ __launch_bounds__(256) void gemm_bf16(
    const short* __restrict__ A, const short* __restrict__ B,
    float* __restrict__ C, int K, int ldc) {
  __shared__ short sA[4096];
  __shared__ short sB[4096];
  const int t = threadIdx.x;
  const int w = t >> 6;
  const int lane = t & 63;
  const int quad = lane >> 4;
  const int l16 = lane & 15;
  const int tm = blockIdx.y * 128;
  const int tn = blockIdx.x * 128;
  const int srow = lane >> 2;
  const int scol = (lane & 3) * 8;
  const int mblk = (w & 1) * 64;
  const int nblk = (w >> 1) * 64;
  f32x4 acc[4][4];
#pragma unroll
  for (int i = 0; i < 4; ++i)
#pragma unroll
    for (int j = 0; j < 4; ++j) acc[i][j] = (f32x4){0.f, 0.f, 0.f, 0.f};

  const short* Ab = A + (size_t)(tm + w * 32 + srow) * K + scol;
  const short* Bb = B + (size_t)(tn + w * 32 + srow) * K + scol;
  const size_t rstep = (size_t)16 * K;

  for (int k0 = 0; k0 < K; k0 += 32) {
    GLDS16(Ab + k0, sA + (w * 2 + 0) * 512);
    GLDS16(Ab + rstep + k0, sA + (w * 2 + 1) * 512);
    GLDS16(Bb + k0, sB + (w * 2 + 0) * 512);
    GLDS16(Bb + rstep + k0, sB + (w * 2 + 1) * 512);
    __syncthreads();
    bf16x8 af[4], bfv[4];
#pragma unroll
    for (int ms = 0; ms < 4; ++ms)
      af[ms] = *(const bf16x8*)&sA[(mblk + ms * 16 + l16) * 32 + quad * 8];
#pragma unroll
    for (int ns = 0; ns < 4; ++ns)
      bfv[ns] = *(const bf16x8*)&sB[(nblk + ns * 16 + l16) * 32 + quad * 8];
#pragma unroll
    for (int ms = 0; ms < 4; ++ms)
#pragma unroll
      for (int ns = 0; ns < 4; ++ns)
        acc[ms][ns] = __builtin_amdgcn_mfma_f32_16x16x32_bf16(
            af[ms], bfv[ns], acc[ms][ns], 0, 0, 0);
    __syncthreads();
  }
#pragma unroll
  for (int ms = 0; ms < 4; ++ms)
#pragma unroll
    for (int ns = 0; ns < 4; ++ns) {
      const int row = tm + mblk + ms * 16 + quad * 4;
      const int col = tn + nblk + ns * 16 + l16;
#pragma unroll
      for (int r = 0; r < 4; ++r)
        C[(size_t)(row + r) * ldc + col] = acc[ms][ns][r];
    }
}

// ---------------------------------------------------------------------------
// RMSNorm(+1+w) then RoPE, in-place on q (16 heads) and k (4 heads).
// ---------------------------------------------------------------------------
__global__ __launch_bounds__(256) void rms_rope(
    float* __restrict__ qkv,
    const float* __restrict__ cosb, const float* __restrict__ sinb,
    const float* __restrict__ qw, const float* __restrict__ kw) {
  const int unit = blockIdx.x * 4 + (threadIdx.x >> 6);
  const int lane = threadIdx.x & 63;
  const int total_q = S_LEN * NH;
  float* base;
  const float* w;
  int pos;
  if (unit < total_q) {
    pos = unit >> 4;
    int head = unit & 15;
    base = qkv + (size_t)pos * QKV_W + head * DH;
    w = qw;
  } else {
    int u = unit - total_q;
    pos = u >> 2;
    int head = u & 3;
    base = qkv + (size_t)pos * QKV_W + 2048 + head * DH;
    w = kw;
  }
  float x0 = base[lane];
  float x1 = base[lane + 64];
  float ss = x0 * x0 + x1 * x1;
#pragma unroll
  for (int off = 32; off > 0; off >>= 1) ss += __shfl_xor(ss, off);
  float r = rsqrtf(ss * (1.0f / 128.0f) + EPS);
  float n0 = x0 * r * (1.0f + w[lane]);
  float n1 = x1 * r * (1.0f + w[lane + 64]);
  float c0 = cosb[(size_t)pos * DH + lane];
  float c1 = cosb[(size_t)pos * DH + lane + 64];
  float s0 = sinb[(size_t)pos * DH + lane];
  float s1 = sinb[(size_t)pos * DH + lane + 64];
  base[lane]      = n0 * c0 - n1 * s0;
  base[lane + 64] = n1 * c1 + n0 * s1;
}

// ---------------------------------------------------------------------------
// Fused K/V pack (one launch).  Blocks [0,2048): pack_k — Kbf pre-swizzled
// rows (d ^= (key&7)<<3) + Klo residual for current keys.  Blocks
// [2048,2560): pack_vt — Vt[4][128][4096] pre-swizzled 64-key chunks
// (c ^= (d&7)<<3).
// ---------------------------------------------------------------------------
__global__ __launch_bounds__(256) void pack_kv(
    const float* __restrict__ qkv, const float* __restrict__ kcache,
    const float* __restrict__ vcache, short* __restrict__ Kbf,
    short* __restrict__ Klo, short* __restrict__ Vt) {
  __shared__ float tile[64][65];
  const int b = blockIdx.x;
  const int t = threadIdx.x;
  if (b < 2048) {
    const int idx = b * 256 + t;
    const int e4 = idx * 4;
    const int kvh = e4 >> 19;
    const int rem = e4 & ((1 << 19) - 1);
    const int key = rem >> 7;
    const int d = rem & 127;
    const int dsw = d ^ ((key & 7) << 3);     // in-row XOR swizzle
    if (key < CACHE_LEN) {
      float4 v = *(const float4*)(kcache + (((size_t)kvh * CACHE_LEN + key) << 7) + d);
      short4 o;
      o.x = f2bf(v.x); o.y = f2bf(v.y); o.z = f2bf(v.z); o.w = f2bf(v.w);
      *(short4*)(Kbf + (size_t)(e4 - d) + dsw) = o;
    } else {
      float4 v = *(const float4*)(qkv + (size_t)(key - CACHE_LEN) * QKV_W + 2048 + kvh * DH + d);
      short4 o;
      o.x = f2bf(v.x); o.y = f2bf(v.y); o.z = f2bf(v.z); o.w = f2bf(v.w);
      *(short4*)(Kbf + (size_t)(e4 - d) + dsw) = o;
      short4 ol;
      ol.x = f2bf(v.x - bf2f(o.x));
      ol.y = f2bf(v.y - bf2f(o.y));
      ol.z = f2bf(v.z - bf2f(o.z));
      ol.w = f2bf(v.w - bf2f(o.w));
      *(short4*)(Klo + ((size_t)kvh * 2048 + (key - CACHE_LEN)) * 128 + dsw) = ol;
    }
  } else {
    const int j = b - 2048;                    // 0..511
    const int key0 = (j & 63) * 64;
    const int d0 = ((j >> 6) & 1) * 64;
    const int kvh = j >> 7;
    const int c = t & 63;
    const int r0 = t >> 6;
#pragma unroll
    for (int i = 0; i < 16; ++i) {
      int r = r0 + i * 4;
      int key = key0 + r;
      float v;
      if (key < CACHE_LEN)
        v = vcache[(((size_t)kvh * CACHE_LEN + key) << 7) + d0 + c];
      else
        v = qkv[(size_t)(key - CACHE_LEN) * QKV_W + 2560 + kvh * DH + d0 + c];
      tile[r][c] = v;
    }
    __syncthreads();
#pragma unroll
    for (int i = 0; i < 16; ++i) {
      int wr = r0 + i * 4;
      int csw = c ^ (((d0 + wr) & 7) << 3);   // in-chunk XOR swizzle
      Vt[((size_t)kvh * DH + d0 + wr) * 4096 + key0 + csw] = f2bf(tile[c][wr]);
    }
  }
}

// ---------------------------------------------------------------------------
// Stage one 128-key K/V tile into an LDS buffer via global_load_lds (16B).
// buf layout (shorts): [0..16383]=K(key*128+e), [16384..32767]=Vt(d*128+key)
// ---------------------------------------------------------------------------
static __device__ __forceinline__ void stage_kv128(
    const short* Kb, const short* Vb, short* buf, int key0, int w, int lane) {
#pragma unroll
  for (int i = 0; i < 4; ++i)
    GLDS16(Kb + ((size_t)key0 + w * 16 + i * 4) * 128 + lane * 8,
           buf + (w * 16 + i * 4) * 128);
#pragma unroll
  for (int i = 0; i < 4; ++i)
    GLDS16(Vb + (size_t)(w * 16 + i * 4 + (lane >> 4)) * 4096 + key0 +
               (lane & 15) * 8,
           buf + 16384 + (w * 16 + i * 4) * 128);
}

// ---------------------------------------------------------------------------
// FUSED attention: lyra (blockIdx.x 0..7, hj=x, qt=y) + vanilla (x 8..15,
// hj=x-8, qt=31-y so heavy causal blocks dispatch first).  512 blocks on
// 256 CUs at 1 block/CU (160KB LDS) -> 2 sequential blocks/CU; the grid
// mix load-balances vanilla's variable causal work against lyra's constant
// work (avg ~41 tile-units/CU vs 49 serial-makespan).  Bodies are the
// R8-verified kernels verbatim; LDS declarations shared (identical shapes);
// linear%8 == hj for both halves keeps the per-XCD K/V L2 pinning.
// ---------------------------------------------------------------------------
__global__ __launch_bounds__(512) void attn_fused(
    const float* __restrict__ qkv,
    const short* __restrict__ Kbf,   // [4][4096][128] pre-swizzled rows
    const short* __restrict__ Klo,   // [4][2048][128] residuals, same swizzle
    const short* __restrict__ Vtb,   // [4][128][4096] pre-swizzled 64-chunks
    float* __restrict__ wout,
    float* __restrict__ vinv,        // [8][2048] 1/rowsum
    short* __restrict__ combined_bf) {
  __shared__ short sKV[2][32768];    // 2 x (K 32KB | Vt 32KB)
  __shared__ short sP[8][2][1024];   // per-wave, per-group [16][64]
  const int bx = blockIdx.x;
  const int t = threadIdx.x;
  const int w = t >> 6;
  const int lane = t & 63;
  const int quad = lane >> 4;
  const int l16 = lane & 15;
  const int wr = w >> 2;             // 0..1 : 32 rows
  const int wc = w & 3;              // 0..3 : 32-key slice of 128
  const int swx = (l16 & 7) << 4;    // byte XOR for swizzled ds_read_b128
  const int voff = (wc >> 1) * 128 + ((((wc & 1) * 64) + quad * 16) ^ swx);

  if (bx < 8) {
    // ------------------------------ LYRA ------------------------------
    const int hj = bx;
    const int qt = blockIdx.y;
    const int kvh = hj >> 1;
    const int row0 = qt * 64;

    bf16x8 qf[2][4];
#pragma unroll
    for (int g = 0; g < 2; ++g) {
      const float* qrow =
          qkv + (size_t)(row0 + wr * 32 + g * 16 + l16) * QKV_W + (8 + hj) * DH;
#pragma unroll
      for (int ks = 0; ks < 4; ++ks) {
        float4 f0 = *(const float4*)(qrow + ks * 32 + quad * 8);
        float4 f1 = *(const float4*)(qrow + ks * 32 + quad * 8 + 4);
        qf[g][ks][0] = f2bf(f0.x * SCALE); qf[g][ks][1] = f2bf(f0.y * SCALE);
        qf[g][ks][2] = f2bf(f0.z * SCALE); qf[g][ks][3] = f2bf(f0.w * SCALE);
        qf[g][ks][4] = f2bf(f1.x * SCALE); qf[g][ks][5] = f2bf(f1.y * SCALE);
        qf[g][ks][6] = f2bf(f1.z * SCALE); qf[g][ks][7] = f2bf(f1.w * SCALE);
      }
    }
    bf16x8 onesf;
#pragma unroll
    for (int i = 0; i < 8; ++i) onesf[i] = (short)0x3F80;  // bf16 1.0

    f32x4 accO[2][8];
#pragma unroll
    for (int g = 0; g < 2; ++g)
#pragma unroll
      for (int i = 0; i < 8; ++i) accO[g][i] = (f32x4){0.f, 0.f, 0.f, 0.f};
    f32x4 accL[2];
    accL[0] = (f32x4){0.f, 0.f, 0.f, 0.f};
    accL[1] = (f32x4){0.f, 0.f, 0.f, 0.f};

    const short* Kb = Kbf + (size_t)kvh * 4096 * DH;
    const short* Vb = Vtb + (size_t)kvh * DH * 4096;

    stage_kv128(Kb, Vb, &sKV[0][0], 0, w, lane);

    int b = 0;
    for (int kt = 0; kt < 32; ++kt) {
      asm volatile("s_waitcnt vmcnt(0)" ::: "memory");
      __builtin_amdgcn_s_barrier();
      __builtin_amdgcn_sched_barrier(0);

      if (kt < 31)
        stage_kv128(Kb, Vb, &sKV[b ^ 1][0], (kt + 1) * 128, w, lane);

      const char* Ksc = (const char*)&sKV[b][0];
      const char* Vsc = (const char*)&sKV[b][16384];

      f32x4 accS[2][2];
#pragma unroll
      for (int g = 0; g < 2; ++g)
#pragma unroll
        for (int s = 0; s < 2; ++s)
          accS[g][s] = (f32x4){-LYRA_C, -LYRA_C, -LYRA_C, -LYRA_C};
      __builtin_amdgcn_s_setprio(1);
#pragma unroll
      for (int s = 0; s < 2; ++s) {
        const char* krow = Ksc + (wc * 32 + s * 16 + l16) * 256;
#pragma unroll
        for (int ks = 0; ks < 4; ++ks) {
          bf16x8 bk = *(const bf16x8*)(krow + ((ks * 64 + quad * 16) ^ swx));
          accS[0][s] = __builtin_amdgcn_mfma_f32_16x16x32_bf16(qf[0][ks], bk, accS[0][s], 0, 0, 0);
          accS[1][s] = __builtin_amdgcn_mfma_f32_16x16x32_bf16(qf[1][ks], bk, accS[1][s], 0, 0, 0);
        }
      }
      __builtin_amdgcn_s_setprio(0);

      const int base = kt * 128 + wc * 32;
#pragma unroll
      for (int g = 0; g < 2; ++g) {
        short* sPg = &sP[w][g][0];
#pragma unroll
        for (int s = 0; s < 2; ++s) {
          const int col = base + s * 16 + l16;
#pragma unroll
          for (int r = 0; r < 4; ++r) {
            const int row = quad * 4 + r;
            const int grow = row0 + wr * 32 + g * 16 + row;
            float z = accS[g][s][r];
            if ((col - CACHE_LEN) > grow) z += 1.0f;
            const int sl = (s * 2 + (l16 >> 3)) ^ (row & 7);
            sPg[row * 64 + sl * 8 + (l16 & 7)] = f2bf(__expf(z));
          }
        }
      }

      __builtin_amdgcn_s_setprio(1);
      bf16x8 ap0 = *(const bf16x8*)&sP[w][0][l16 * 64 + ((quad ^ (l16 & 7)) << 3)];
      bf16x8 ap1 = *(const bf16x8*)&sP[w][1][l16 * 64 + ((quad ^ (l16 & 7)) << 3)];
      accL[0] = __builtin_amdgcn_mfma_f32_16x16x32_bf16(ap0, onesf, accL[0], 0, 0, 0);
      accL[1] = __builtin_amdgcn_mfma_f32_16x16x32_bf16(ap1, onesf, accL[1], 0, 0, 0);
#pragma unroll
      for (int t8 = 0; t8 < 8; ++t8) {
        bf16x8 bv = *(const bf16x8*)(Vsc + (t8 * 16 + l16) * 256 + voff);
        accO[0][t8] = __builtin_amdgcn_mfma_f32_16x16x32_bf16(ap0, bv, accO[0][t8], 0, 0, 0);
        accO[1][t8] = __builtin_amdgcn_mfma_f32_16x16x32_bf16(ap1, bv, accO[1][t8], 0, 0, 0);
      }
      __builtin_amdgcn_s_setprio(0);

      b ^= 1;
    }

    __syncthreads();
    float* sO = (float*)&sKV[0][0];
    float* sLa = (float*)&sP[0][0][0];  // [3][64]
    if (wc != 0) {
      float* dst = sO + (size_t)(wc - 1) * 8192;
#pragma unroll
      for (int g = 0; g < 2; ++g)
#pragma unroll
        for (int t8 = 0; t8 < 8; ++t8)
#pragma unroll
          for (int r = 0; r < 4; ++r) {
            const int rl = wr * 32 + g * 16 + quad * 4 + r;
            dst[rl * 128 + t8 * 16 + l16] = accO[g][t8][r];
          }
      if (l16 == 0) {
#pragma unroll
        for (int g = 0; g < 2; ++g)
#pragma unroll
          for (int r = 0; r < 4; ++r)
            sLa[(wc - 1) * 64 + wr * 32 + g * 16 + quad * 4 + r] = accL[g][r];
      }
    }
    __syncthreads();
    if (wc == 0) {
#pragma unroll
      for (int g = 0; g < 2; ++g) {
        float linv[4];
#pragma unroll
        for (int r = 0; r < 4; ++r) {
          const int rl = wr * 32 + g * 16 + quad * 4 + r;
          linv[r] = 1.0f / (accL[g][r] + sLa[rl] + sLa[64 + rl] + sLa[128 + rl]);
        }
#pragma unroll
        for (int t8 = 0; t8 < 8; ++t8)
#pragma unroll
          for (int r = 0; r < 4; ++r) {
            const int rl = wr * 32 + g * 16 + quad * 4 + r;
            const int c = t8 * 16 + l16;
            float o = accO[g][t8][r] + sO[rl * 128 + c] + sO[8192 + rl * 128 + c] +
                      sO[16384 + rl * 128 + c];
            combined_bf[(size_t)(row0 + rl) * HID + (8 + hj) * DH + c] =
                f2bf(o * linv[r]);
          }
      }
    }
  } else {
    // ----------------------------- VANILLA ----------------------------
    const int hj = bx - 8;
    const int qt = 31 - blockIdx.y;   // heavy blocks dispatch first
    const int kvh = hj >> 1;
    const int row0 = qt * 64;
    const int nt = qt / 2 + 1;        // number of 128-key tiles (causal)

    bf16x8 qh[2][4], ql[2][4];
#pragma unroll
    for (int g = 0; g < 2; ++g) {
      const float* qrow =
          qkv + (size_t)(row0 + wr * 32 + g * 16 + l16) * QKV_W + hj * DH;
#pragma unroll
      for (int ks = 0; ks < 4; ++ks) {
#pragma unroll
        for (int e = 0; e < 8; ++e) {
          float x = qrow[ks * 32 + quad * 8 + e] * SCALE;
          short h = f2bf(x);
          qh[g][ks][e] = h;
          ql[g][ks][e] = f2bf(x - bf2f(h));
        }
      }
    }

    f32x4 accO[2][8];
#pragma unroll
    for (int g = 0; g < 2; ++g)
#pragma unroll
      for (int i = 0; i < 8; ++i) accO[g][i] = (f32x4){0.f, 0.f, 0.f, 0.f};
    float accR[2][4] = {{0.f, 0.f, 0.f, 0.f}, {0.f, 0.f, 0.f, 0.f}};

    const short* Kh = Kbf + ((size_t)kvh * 4096 + 2048) * DH;
    const short* Kl = Klo + (size_t)kvh * 2048 * DH;
    const short* Vb = Vtb + (size_t)kvh * DH * 4096 + 2048;  // current-v cols
    float* wrow = wout + (size_t)hj * S_LEN * S_LEN;

    stage_kv128(Kh, Vb, &sKV[0][0], 0, w, lane);

    int b = 0;
    for (int kt = 0; kt < nt; ++kt) {
      asm volatile("s_waitcnt vmcnt(0)" ::: "memory");
      __builtin_amdgcn_s_barrier();
      __builtin_amdgcn_sched_barrier(0);

      if (kt < nt - 1)
        stage_kv128(Kh, Vb, &sKV[b ^ 1][0], (kt + 1) * 128, w, lane);

      const int key0 = kt * 128;
      bf16x8 klf[2][4];
#pragma unroll
      for (int s = 0; s < 2; ++s)
#pragma unroll
        for (int ks = 0; ks < 4; ++ks)
          klf[s][ks] = *(const bf16x8*)(
              Kl + (size_t)(key0 + wc * 32 + s * 16 + l16) * 128 +
              ((ks * 32 + quad * 8) ^ ((l16 & 7) << 3)));

      const char* Khs = (const char*)&sKV[b][0];
      const char* Vsc = (const char*)&sKV[b][16384];

      f32x4 accS[2][2];
#pragma unroll
      for (int g = 0; g < 2; ++g)
#pragma unroll
        for (int s = 0; s < 2; ++s)
          accS[g][s] = (f32x4){-LYRA_C, -LYRA_C, -LYRA_C, -LYRA_C};
      __builtin_amdgcn_s_setprio(1);
#pragma unroll
      for (int s = 0; s < 2; ++s) {
        const char* krh = Khs + (wc * 32 + s * 16 + l16) * 256;
#pragma unroll
        for (int ks = 0; ks < 4; ++ks) {
          bf16x8 kh = *(const bf16x8*)(krh + ((ks * 64 + quad * 16) ^ swx));
          accS[0][s] = __builtin_amdgcn_mfma_f32_16x16x32_bf16(qh[0][ks], kh, accS[0][s], 0, 0, 0);
          accS[1][s] = __builtin_amdgcn_mfma_f32_16x16x32_bf16(qh[1][ks], kh, accS[1][s], 0, 0, 0);
          accS[0][s] = __builtin_amdgcn_mfma_f32_16x16x32_bf16(ql[0][ks], kh, accS[0][s], 0, 0, 0);
          accS[1][s] = __builtin_amdgcn_mfma_f32_16x16x32_bf16(ql[1][ks], kh, accS[1][s], 0, 0, 0);
          accS[0][s] = __builtin_amdgcn_mfma_f32_16x16x32_bf16(qh[0][ks], klf[s][ks], accS[0][s], 0, 0, 0);
          accS[1][s] = __builtin_amdgcn_mfma_f32_16x16x32_bf16(qh[1][ks], klf[s][ks], accS[1][s], 0, 0, 0);
        }
      }
      __builtin_amdgcn_s_setprio(0);

      const bool diag = (kt == nt - 1);
#pragma unroll
      for (int g = 0; g < 2; ++g) {
        short* sPg = &sP[w][g][0];
        float pr[4] = {0.f, 0.f, 0.f, 0.f};
#pragma unroll
        for (int s = 0; s < 2; ++s) {
          const int col = key0 + wc * 32 + s * 16 + l16;
#pragma unroll
          for (int r = 0; r < 4; ++r) {
            const int row = quad * 4 + r;
            const int grow = row0 + wr * 32 + g * 16 + row;
            float p = __expf(accS[g][s][r]);
            if (diag && col > grow) p = 0.f;
            pr[r] += p;
            const int sl = (s * 2 + (l16 >> 3)) ^ (row & 7);
            sPg[row * 64 + sl * 8 + (l16 & 7)] = f2bf(p);
            wrow[(size_t)grow * S_LEN + col] = p;
          }
        }
#pragma unroll
        for (int r = 0; r < 4; ++r) {
          float v = pr[r];
          v += __shfl_xor(v, 1);
          v += __shfl_xor(v, 2);
          v += __shfl_xor(v, 4);
          v += __shfl_xor(v, 8);
          accR[g][r] += v;
        }
      }

      __builtin_amdgcn_s_setprio(1);
      bf16x8 ap0 = *(const bf16x8*)&sP[w][0][l16 * 64 + ((quad ^ (l16 & 7)) << 3)];
      bf16x8 ap1 = *(const bf16x8*)&sP[w][1][l16 * 64 + ((quad ^ (l16 & 7)) << 3)];
#pragma unroll
      for (int t8 = 0; t8 < 8; ++t8) {
        bf16x8 bv = *(const bf16x8*)(Vsc + (t8 * 16 + l16) * 256 + voff);
        accO[0][t8] = __builtin_amdgcn_mfma_f32_16x16x32_bf16(ap0, bv, accO[0][t8], 0, 0, 0);
        accO[1][t8] = __builtin_amdgcn_mfma_f32_16x16x32_bf16(ap1, bv, accO[1][t8], 0, 0, 0);
      }
      __builtin_amdgcn_s_setprio(0);

      b ^= 1;
    }

    __syncthreads();
    float* sO = (float*)&sKV[0][0];
    float* sLa = (float*)&sP[0][0][0];  // [3][64]
    if (wc != 0) {
      float* dst = sO + (size_t)(wc - 1) * 8192;
#pragma unroll
      for (int g = 0; g < 2; ++g)
#pragma unroll
        for (int t8 = 0; t8 < 8; ++t8)
#pragma unroll
          for (int r = 0; r < 4; ++r) {
            const int rl = wr * 32 + g * 16 + quad * 4 + r;
            dst[rl * 128 + t8 * 16 + l16] = accO[g][t8][r];
          }
      if (l16 == 0) {
#pragma unroll
        for (int g = 0; g < 2; ++g)
#pragma unroll
          for (int r = 0; r < 4; ++r)
            sLa[(wc - 1) * 64 + wr * 32 + g * 16 + quad * 4 + r] = accR[g][r];
      }
    }
    __syncthreads();
    if (wc == 0) {
#pragma unroll
      for (int g = 0; g < 2; ++g) {
        float linv[4];
#pragma unroll
        for (int r = 0; r < 4; ++r) {
          const int rl = wr * 32 + g * 16 + quad * 4 + r;
          linv[r] = 1.0f / (accR[g][r] + sLa[rl] + sLa[64 + rl] + sLa[128 + rl]);
        }
        if (l16 == 0) {
#pragma unroll
          for (int r = 0; r < 4; ++r)
            vinv[hj * S_LEN + row0 + wr * 32 + g * 16 + quad * 4 + r] = linv[r];
        }
#pragma unroll
        for (int t8 = 0; t8 < 8; ++t8)
#pragma unroll
          for (int r = 0; r < 4; ++r) {
            const int rl = wr * 32 + g * 16 + quad * 4 + r;
            const int c = t8 * 16 + l16;
            float o = accO[g][t8][r] + sO[rl * 128 + c] + sO[8192 + rl * 128 + c] +
                      sO[16384 + rl * 128 + c];
            combined_bf[(size_t)(row0 + rl) * HID + hj * DH + c] =
                f2bf(o * linv[r]);
          }
      }
    }
  }
}

// ---------------------------------------------------------------------------
// FUSED final GEMM + vnorm.  Blocks [0,256): attn_output = combined_bf *
// Wo_bf^T (the R8 gemm_bf16 body, K=2048, ldc=2048).  Blocks [256,16640):
// one wout row each — scale by stored 1/rowsum, zero-fill j > row.  The two
// halves touch disjoint data; vnorm's HBM traffic overlaps the MFMA GEMM.
// ---------------------------------------------------------------------------
__global__ __launch_bounds__(256) void gemm_vnorm(
    const short* __restrict__ A, const short* __restrict__ B,
    float* __restrict__ C, const float* __restrict__ vinv,
    float* __restrict__ wout) {
  __shared__ short sA[4096];
  __shared__ short sB[4096];
  const int blk = blockIdx.x;
  const int t = threadIdx.x;
  if (blk < 256) {
    const int K = 2048, ldc = 2048;
    const int w = t >> 6;
    const int lane = t & 63;
    const int quad = lane >> 4;
    const int l16 = lane & 15;
    const int tm = (blk >> 4) * 128;
    const int tn = (blk & 15) * 128;
    const int srow = lane >> 2;
    const int scol = (lane & 3) * 8;
    const int mblk = (w & 1) * 64;
    const int nblk = (w >> 1) * 64;
    f32x4 acc[4][4];
#pragma unroll
    for (int i = 0; i < 4; ++i)
#pragma unroll
      for (int j = 0; j < 4; ++j) acc[i][j] = (f32x4){0.f, 0.f, 0.f, 0.f};

    const short* Ab = A + (size_t)(tm + w * 32 + srow) * K + scol;
    const short* Bb = B + (size_t)(tn + w * 32 + srow) * K + scol;
    const size_t rstep = (size_t)16 * K;

    for (int k0 = 0; k0 < K; k0 += 32) {
      GLDS16(Ab + k0, sA + (w * 2 + 0) * 512);
      GLDS16(Ab + rstep + k0, sA + (w * 2 + 1) * 512);
      GLDS16(Bb + k0, sB + (w * 2 + 0) * 512);
      GLDS16(Bb + rstep + k0, sB + (w * 2 + 1) * 512);
      __syncthreads();
      bf16x8 af[4], bfv[4];
#pragma unroll
      for (int ms = 0; ms < 4; ++ms)
        af[ms] = *(const bf16x8*)&sA[(mblk + ms * 16 + l16) * 32 + quad * 8];
#pragma unroll
      for (int ns = 0; ns < 4; ++ns)
        bfv[ns] = *(const bf16x8*)&sB[(nblk + ns * 16 + l16) * 32 + quad * 8];
#pragma unroll
      for (int ms = 0; ms < 4; ++ms)
#pragma unroll
        for (int ns = 0; ns < 4; ++ns)
          acc[ms][ns] = __builtin_amdgcn_mfma_f32_16x16x32_bf16(
              af[ms], bfv[ns], acc[ms][ns], 0, 0, 0);
      __syncthreads();
    }
#pragma unroll
    for (int ms = 0; ms < 4; ++ms)
#pragma unroll
      for (int ns = 0; ns < 4; ++ns) {
        const int row = tm + mblk + ms * 16 + quad * 4;
        const int col = tn + nblk + ns * 16 + l16;
#pragma unroll
        for (int r = 0; r < 4; ++r)
          C[(size_t)(row + r) * ldc + col] = acc[ms][ns][r];
      }
  } else {
    const int j0 = blk - 256;
    const int row = j0 & 2047;
    const int h = j0 >> 11;
    float* p = wout + (size_t)h * S_LEN * S_LEN + (size_t)row * S_LEN;
    const float inv = vinv[h * S_LEN + row];
#pragma unroll
    for (int i = 0; i < 2; ++i) {
      const int j = (t + i * 256) * 4;
      float4 v;
      if (j > row) {
        v = make_float4(0.f, 0.f, 0.f, 0.f);
      } else if (j + 3 <= row) {
        v = *(const float4*)(p + j);
        v.x *= inv; v.y *= inv; v.z *= inv; v.w *= inv;
      } else {
        v = *(const float4*)(p + j);
        v.x = (j + 0 <= row) ? v.x * inv : 0.f;
        v.y = (j + 1 <= row) ? v.y * inv : 0.f;
        v.z = (j + 2 <= row) ? v.z * inv : 0.f;
        v.w = (j + 3 <= row) ? v.w * inv : 0.f;
      }
      *(float4*)(p + j) = v;
    }
  }
}

// ---------------------------------------------------------------------------
extern "C" void kernel_launch(void* const* d_in, const int* in_sizes, int n_in,
                              void* d_out, int out_size, void* d_ws, size_t ws_size,
                              hipStream_t stream) {
  (void)in_sizes; (void)n_in; (void)out_size; (void)ws_size;
  const float* hidden = (const float*)d_in[0];
  const float* cosb   = (const float*)d_in[1];
  const float* sinb   = (const float*)d_in[2];
  const float* kcache = (const float*)d_in[4];
  const float* vcache = (const float*)d_in[5];
  const float* Wq = (const float*)d_in[6];
  const float* Wk = (const float*)d_in[7];
  const float* Wv = (const float*)d_in[8];
  const float* Wo = (const float*)d_in[9];
  const float* qw = (const float*)d_in[10];
  const float* kw = (const float*)d_in[11];

  float* out  = (float*)d_out;                     // attn_output [2048*2048]
  float* wout = out + (size_t)4194304;             // vanilla_w   [8*2048*2048]

  // d_ws: qkv f32 | Kbf | Vtb | combined_bf | Wo_bf | Klo | vinv
  float* qkv = (float*)d_ws;                       // [2048 x 3072] f32
  short* Kbf = (short*)(qkv + (size_t)2048 * QKV_W);
  short* Vtb = Kbf + (size_t)4 * 4096 * DH;
  short* combined_bf = Vtb + (size_t)4 * DH * 4096;   // [2048 x 2048] bf16
  short* Wo_bf = combined_bf + (size_t)2048 * HID;    // [2048 x 2048] bf16
  short* Klo  = Wo_bf + (size_t)2048 * HID;           // [4][2048][128] bf16
  float* vinv = (float*)(Klo + (size_t)4 * 2048 * DH); // [8][2048] f32

  // transient scratch inside wout (consumed by gemm qkv before attn_fused
  // overwrites wout):
  short* hidden_bf = (short*)wout;                    // [2048 x 2048] bf16
  short* Wqkv_bf = hidden_bf + (size_t)2048 * HID;    // [3072 x 2048] bf16

  pack_all<<<dim3(7168), 256, 0, stream>>>(hidden, Wq, Wk, Wv, Wo,
                                           hidden_bf, Wqkv_bf, Wo_bf);
  gemm_bf16<<<dim3(24, 16), 256, 0, stream>>>(hidden_bf, Wqkv_bf, qkv, 2048, QKV_W);
  rms_rope<<<dim3(10240), 256, 0, stream>>>(qkv, cosb, sinb, qw, kw);
  pack_kv<<<dim3(2560), 256, 0, stream>>>(qkv, kcache, vcache, Kbf, Klo, Vtb);
  attn_fused<<<dim3(16, 32), 512, 0, stream>>>(qkv, Kbf, Klo, Vtb, wout, vinv,
                                               combined_bf);
  gemm_vnorm<<<dim3(16640), 256, 0, stream>>>(combined_bf, Wo_bf, out, vinv, wout);
}